// Round 12
// baseline (1553.800 us; speedup 1.0000x reference)
//
#include <hip/hip_runtime.h>
#include <math.h>

#define BN_EPS 1e-5f
constexpr int Bc = 8, Nc = 8192, Sc = 1024, CINc = 64;

typedef float v2f __attribute__((ext_vector_type(2)));

// ---------------- DPP helpers ----------------
template <int CTRL, int RMASK>
__device__ __forceinline__ unsigned long long dpp_maxu64(unsigned long long k) {
  int lo = (int)(unsigned)k, hi = (int)(unsigned)(k >> 32);
  int olo = __builtin_amdgcn_update_dpp(lo, lo, CTRL, RMASK, 0xF, false);
  int ohi = __builtin_amdgcn_update_dpp(hi, hi, CTRL, RMASK, 0xF, false);
  unsigned long long ok = ((unsigned long long)(unsigned)ohi << 32) | (unsigned)olo;
  return ok > k ? ok : k;
}
template <int CTRL, int RMASK>
__device__ __forceinline__ v2f dpp_sumstep2(v2f v) {
  int olo = __builtin_amdgcn_update_dpp(0, __float_as_int(v.x), CTRL, RMASK, 0xF, false);
  int ohi = __builtin_amdgcn_update_dpp(0, __float_as_int(v.y), CTRL, RMASK, 0xF, false);
  v2f o = {__int_as_float(olo), __int_as_float(ohi)};
  return v + o;
}
__device__ __forceinline__ v2f dpp_sum64v2(v2f v) {
  v = dpp_sumstep2<0x111, 0xF>(v);
  v = dpp_sumstep2<0x112, 0xF>(v);
  v = dpp_sumstep2<0x114, 0xF>(v);
  v = dpp_sumstep2<0x118, 0xF>(v);
  v = dpp_sumstep2<0x142, 0xA>(v);
  v = dpp_sumstep2<0x143, 0xC>(v);
  return v;  // lane63 holds total
}
template <int CTRL>
__device__ __forceinline__ v2f dpp_pkmax(v2f v) {
  int ox = __builtin_amdgcn_update_dpp(__float_as_int(v.x), __float_as_int(v.x), CTRL, 0xF, 0xF, false);
  int oy = __builtin_amdgcn_update_dpp(__float_as_int(v.y), __float_as_int(v.y), CTRL, 0xF, 0xF, false);
  v2f o = {__int_as_float(ox), __int_as_float(oy)};
  return __builtin_elementwise_max(v, o);
}
template <int CTRL>
__device__ __forceinline__ v2f dpp_pkmin(v2f v) {
  int ox = __builtin_amdgcn_update_dpp(__float_as_int(v.x), __float_as_int(v.x), CTRL, 0xF, 0xF, false);
  int oy = __builtin_amdgcn_update_dpp(__float_as_int(v.y), __float_as_int(v.y), CTRL, 0xF, 0xF, false);
  v2f o = {__int_as_float(ox), __int_as_float(oy)};
  return __builtin_elementwise_min(v, o);
}

// ---------------- shared pproj body (P[n][64] = W_pts . points + bias) ----------------
__device__ __forceinline__ void pproj_body(int i, const float* __restrict__ pts,
                                           const float* __restrict__ wl,
                                           const float* __restrict__ bl,
                                           float* __restrict__ P) {
  int b = i >> 13, n = i & 8191;
  const float* pb = pts + (size_t)b * CINc * Nc + n;
  v2f acc[32];
  const v2f* bl2 = (const v2f*)bl;
#pragma unroll
  for (int o2 = 0; o2 < 32; o2++) acc[o2] = bl2[o2];
  for (int c = 0; c < CINc; c++) {
    float xv = pb[(size_t)c * Nc];
    v2f xv2 = {xv, xv};
    const v2f* wr = (const v2f*)(wl + c * 64);
#pragma unroll
    for (int o2 = 0; o2 < 32; o2++) acc[o2] = __builtin_elementwise_fma(wr[o2], xv2, acc[o2]);
  }
  float4* Pn = (float4*)(P + (size_t)i * 64);
#pragma unroll
  for (int o4 = 0; o4 < 16; o4++)
    Pn[o4] = make_float4(acc[2 * o4].x, acc[2 * o4].y, acc[2 * o4 + 1].x, acc[2 * o4 + 1].y);
}

// ------- mega: blocks 0-7 fps (r8-proven 512t body), 8-135 xyzt, 136-263 pproj0, 264-391 pproj1
__global__ __launch_bounds__(512) void mega_kernel(const float* __restrict__ xyz,
                                                   const float* __restrict__ pts,
                                                   const float* __restrict__ w00,
                                                   const float* __restrict__ b00,
                                                   const float* __restrict__ w10,
                                                   const float* __restrict__ b10,
                                                   float4* __restrict__ xyzT,
                                                   float4* __restrict__ nx,
                                                   float* __restrict__ out0,
                                                   float* __restrict__ P0,
                                                   float* __restrict__ P1) {
  __shared__ alignas(16) char smemc[102528];
  int bid = blockIdx.x, t = threadIdx.x;
  if (bid < 8) {
    float* xs = (float*)smemc;
    float* ys = xs + Nc;
    float* zs = ys + Nc;
    int* idxs = (int*)(smemc + 98304);
    unsigned long long* red = (unsigned long long*)(smemc + 102400);  // [2][8]
    const float* xb = xyz + (size_t)bid * 3 * Nc;
    float px[16], py[16], pz[16], dd[16];
#pragma unroll
    for (int j = 0; j < 16; j++) {
      int n = j * 512 + t;
      float x = xb[n], y = xb[Nc + n], z = xb[2 * Nc + n];
      px[j] = x; py[j] = y; pz[j] = z;
      xs[n] = x; ys[n] = y; zs[n] = z;
      dd[j] = 1e10f;
    }
    int w = t >> 6;
    __syncthreads();
    int curIdx = 0;
    for (int i = 0; i < Sc; i++) {
      float cx = xs[curIdx], cy = ys[curIdx], cz = zs[curIdx];  // LDS broadcast
      if (t == 0) idxs[i] = curIdx;
      float bd = -1.f;
      int bnidx = 0;
#pragma unroll
      for (int j = 0; j < 16; j++) {
        float dx = px[j] - cx, dy = py[j] - cy, dz = pz[j] - cz;
        float d = fmaf(dz, dz, fmaf(dy, dy, dx * dx));
        d = fminf(dd[j], d);
        dd[j] = d;
        if (d > bd) { bd = d; bnidx = j * 512 + t; }  // strict >: first index wins (jnp.argmax)
      }
      unsigned long long key =
          ((unsigned long long)__float_as_uint(bd) << 32) | (unsigned)(~bnidx);
      key = dpp_maxu64<0x111, 0xF>(key);
      key = dpp_maxu64<0x112, 0xF>(key);
      key = dpp_maxu64<0x114, 0xF>(key);
      key = dpp_maxu64<0x118, 0xF>(key);
      key = dpp_maxu64<0x142, 0xA>(key);
      key = dpp_maxu64<0x143, 0xC>(key);
      if ((t & 63) == 63) red[(i & 1) * 8 + w] = key;
      __syncthreads();
      const unsigned long long* rr = red + (i & 1) * 8;
      unsigned long long k2 = rr[0];
#pragma unroll
      for (int u = 1; u < 8; u++) {
        unsigned long long o = rr[u];
        k2 = (o > k2) ? o : k2;
      }
      curIdx = (int)(~(unsigned)(k2 & 0xFFFFFFFFull));
    }
    __syncthreads();
    for (int i2 = t; i2 < Sc; i2 += 512) {
      int idx = idxs[i2];
      float x = xs[idx], y = ys[idx], z = zs[idx];
      nx[bid * Sc + i2] = make_float4(x, y, z, fmaf(z, z, fmaf(y, y, x * x)));
      float* ob = out0 + (size_t)bid * 3 * Sc;
      ob[i2] = x; ob[Sc + i2] = y; ob[2 * Sc + i2] = z;
    }
  } else if (bid < 136) {
    int i = (bid - 8) * 512 + t;
    int b = i >> 13, n = i & 8191;
    const float* xb = xyz + (size_t)b * 3 * Nc;
    float x = xb[n], y = xb[Nc + n], z = xb[2 * Nc + n];
    xyzT[i] = make_float4(x, y, z, fmaf(z, z, fmaf(y, y, x * x)));
  } else {
    bool second = bid >= 264;
    const float* ww = second ? w10 : w00;
    const float* bb = second ? b10 : b00;
    float* PP = second ? P1 : P0;
    float* wl = (float*)smemc;  // 64*64 floats
    float* bl = wl + 64 * 64;
    for (int i2 = t; i2 < 64 * 64; i2 += 512) {
      int c = i2 >> 6, o = i2 & 63;
      wl[i2] = ww[o * 67 + 3 + c];
    }
    if (t < 64) bl[t] = bb[t];
    __syncthreads();
    pproj_body(((bid - (second ? 264 : 136)) * 512) + t, pts, wl, bl, PP);
  }
}

// ---------------- wave-cooperative 32-NN (unchanged) ----------------
__global__ __launch_bounds__(256) void knn_kernel(const float4* __restrict__ xyzT,
                                                  const float4* __restrict__ newxyz,
                                                  int* __restrict__ knn) {
  int lane = threadIdx.x & 63;
  int sub = lane >> 5;
  int l32 = lane & 31;
  int waveId = blockIdx.x * 4 + (threadIdx.x >> 6);
  int q = waveId * 2 + sub;
  int b = q >> 10;
  float4 qv = newxyz[q];
  const float4* pb = xyzT + (size_t)b * Nc;
  unsigned long long lk = ~0ull;
  for (int t0 = 0; t0 < Nc; t0 += 32) {
    float4 p = pb[t0 + l32];
    float dot = fmaf(qv.z, p.z, fmaf(qv.y, p.y, qv.x * p.x));
    float d = fmaf(-2.f, dot, qv.w + p.w);
    unsigned fu = __float_as_uint(d);
    fu ^= (unsigned)(-(int)(fu >> 31)) | 0x80000000u;
    unsigned long long ck = ((unsigned long long)fu << 32) | (unsigned)(t0 + l32);
    unsigned long long worst = __shfl(lk, 31, 32);
    unsigned long long bal = __ballot(ck < worst);
    if (((unsigned)(bal >> (sub * 32))) == 0u) continue;
#pragma unroll
    for (int k = 2; k <= 32; k <<= 1) {
#pragma unroll
      for (int j = k >> 1; j > 0; j >>= 1) {
        unsigned long long o = __shfl_xor(ck, j, 32);
        bool up = ((l32 & k) == 0);
        bool lower = ((l32 & j) == 0);
        unsigned long long mn = (o < ck) ? o : ck;
        unsigned long long mx = (o < ck) ? ck : o;
        ck = (up == lower) ? mn : mx;
      }
    }
    unsigned long long rev = __shfl(ck, 31 - l32, 32);
    unsigned long long m0 = (rev < lk) ? rev : lk;
#pragma unroll
    for (int j = 16; j > 0; j >>= 1) {
      unsigned long long o = __shfl_xor(m0, j, 32);
      bool lower = ((l32 & j) == 0);
      unsigned long long mn = (o < m0) ? o : m0;
      unsigned long long mx = (o < m0) ? m0 : o;
      m0 = lower ? mn : mx;
    }
    lk = m0;
  }
  knn[(size_t)q * 32 + l32] = (int)(lk & 0xFFFFFFFFu);
}

// ---------------- conv1 body (branch-templated, shared smem carve) ----------------
template <int K>
__device__ __forceinline__ void conv1_body(char* smemc, int bidl,
                                           const float4* __restrict__ xyzT,
                                           const float4* __restrict__ nx,
                                           const int* __restrict__ knn,
                                           const float* __restrict__ P,
                                           const float* __restrict__ w0,
                                           float* __restrict__ y,
                                           float* __restrict__ part, int Pos) {
  v2f* wst = (v2f*)smemc;  // 16*64 v2f = 8192 B
  float* wx = (float*)(smemc + 8192);
  float* wy = wx + 64;
  float* wz = wy + 64;
  if (threadIdx.x < 64) {
    int o = threadIdx.x;
    wx[o] = w0[o * 67];
    wy[o] = w0[o * 67 + 1];
    wz[o] = w0[o * 67 + 2];
  }
  __syncthreads();
  int gp = bidl * 256 + threadIdx.x;
  int b = gp / Pos, r = gp % Pos;
  int s = r / K, kk = r & (K - 1);
  int n = knn[((size_t)(b * Sc + s)) * 32 + kk];
  float4 c4 = nx[b * Sc + s];
  float4 p4 = xyzT[(size_t)b * Nc + n];
  v2f dx2 = {p4.x - c4.x, p4.x - c4.x};
  v2f dy2 = {p4.y - c4.y, p4.y - c4.y};
  v2f dz2 = {p4.z - c4.z, p4.z - c4.z};
  const float4* Pn = (const float4*)(P + ((size_t)b * Nc + n) * 64);
  v2f acc[32];
#pragma unroll
  for (int o4 = 0; o4 < 16; o4++) {
    float4 v = Pn[o4];
    acc[2 * o4] = (v2f){v.x, v.y};
    acc[2 * o4 + 1] = (v2f){v.z, v.w};
  }
  const v2f* wx2 = (const v2f*)wx;
  const v2f* wy2 = (const v2f*)wy;
  const v2f* wz2 = (const v2f*)wz;
#pragma unroll
  for (int o2 = 0; o2 < 32; o2++) acc[o2] = __builtin_elementwise_fma(wx2[o2], dx2, acc[o2]);
#pragma unroll
  for (int o2 = 0; o2 < 32; o2++) acc[o2] = __builtin_elementwise_fma(wy2[o2], dy2, acc[o2]);
#pragma unroll
  for (int o2 = 0; o2 < 32; o2++) acc[o2] = __builtin_elementwise_fma(wz2[o2], dz2, acc[o2]);
  float4* yb = (float4*)(y + ((size_t)b * Pos + r) * 64);
#pragma unroll
  for (int o4 = 0; o4 < 16; o4++)
    yb[o4] = make_float4(acc[2 * o4].x, acc[2 * o4].y, acc[2 * o4 + 1].x, acc[2 * o4 + 1].y);
  int lane = threadIdx.x & 63, w = threadIdx.x >> 6;
  int row = w * 4 + (lane >> 4);
  bool lead = (lane & 15) == 15;
#pragma unroll
  for (int o2 = 0; o2 < 32; o2++) {
    float v0 = acc[o2].x, v1 = acc[o2].y;
    v2f s0 = (v2f){v0, v0 * v0};
    s0 = dpp_sumstep2<0x111, 0xF>(s0);
    s0 = dpp_sumstep2<0x112, 0xF>(s0);
    s0 = dpp_sumstep2<0x114, 0xF>(s0);
    s0 = dpp_sumstep2<0x118, 0xF>(s0);
    v2f s1 = (v2f){v1, v1 * v1};
    s1 = dpp_sumstep2<0x111, 0xF>(s1);
    s1 = dpp_sumstep2<0x112, 0xF>(s1);
    s1 = dpp_sumstep2<0x114, 0xF>(s1);
    s1 = dpp_sumstep2<0x118, 0xF>(s1);
    if (lead) { wst[row * 64 + 2 * o2] = s0; wst[row * 64 + 2 * o2 + 1] = s1; }
  }
  __syncthreads();
  if (threadIdx.x < 64) {
    int o = threadIdx.x;
    v2f sv = (v2f){0.f, 0.f};
#pragma unroll
    for (int rr = 0; rr < 16; rr++) sv += wst[rr * 64 + o];
    ((v2f*)part)[(size_t)bidl * 64 + o] = sv;
  }
}

__global__ __launch_bounds__(256) void conv1M_kernel(
    const float4* xyzT, const float4* nx, const int* knn,
    const float* P0, const float* w0a, float* y0a, float* part0, int Pos0,
    const float* P1, const float* w0b, float* y0b, float* part1, int Pos1, int split) {
  __shared__ alignas(16) char smemc[8960];
  if ((int)blockIdx.x < split)
    conv1_body<16>(smemc, blockIdx.x, xyzT, nx, knn, P0, w0a, y0a, part0, Pos0);
  else
    conv1_body<32>(smemc, blockIdx.x - split, xyzT, nx, knn, P1, w0b, y0b, part1, Pos1);
}

// ---------------- bn finalize (merged, runtime C) ----------------
__global__ __launch_bounds__(256) void bnfinM_kernel(
    const float* part0, const float* g0, const float* be0, float* bn0, int C0, int nblk0, float inv0,
    const float* part1, const float* g1, const float* be1, float* bn1, int C1, int nblk1, float inv1,
    int split) {
  const float* part; const float* g; const float* be; float* bn;
  int C, nblk, c; float invcnt;
  if ((int)blockIdx.x < split) {
    part = part0; g = g0; be = be0; bn = bn0; C = C0; nblk = nblk0; invcnt = inv0; c = blockIdx.x;
  } else {
    part = part1; g = g1; be = be1; bn = bn1; C = C1; nblk = nblk1; invcnt = inv1; c = blockIdx.x - split;
  }
  v2f sq = (v2f){0.f, 0.f};
  for (int i = threadIdx.x; i < nblk; i += 256) sq += ((const v2f*)part)[(size_t)i * C + c];
  sq = dpp_sum64v2(sq);
  __shared__ v2f ls[4];
  int w = threadIdx.x >> 6;
  if ((threadIdx.x & 63) == 63) ls[w] = sq;
  __syncthreads();
  if (threadIdx.x == 0) {
    v2f tt = ls[0] + ls[1] + ls[2] + ls[3];
    float m = tt.x * invcnt;
    float v = tt.y * invcnt - m * m;
    float sc = g[c] / sqrtf(v + BN_EPS);
    bn[c * 2] = sc;
    bn[c * 2 + 1] = fmaf(-m, sc, be[c]);
  }
}

// ---------------- convB body (shared smem carve) ----------------
template <int CI, int CO, int K>
__device__ __forceinline__ void convB_body(char* smemc, int bidl,
                                           const float* __restrict__ yin,
                                           const float* __restrict__ wt,
                                           const float* __restrict__ bb,
                                           const float* __restrict__ bn,
                                           float* __restrict__ yout,
                                           float* __restrict__ ymax,
                                           float* __restrict__ ymin,
                                           float* __restrict__ part, int Pos) {
  constexpr int COq = CO / 4;
  constexpr int COq2 = COq / 2;
  float* wl = (float*)smemc;       // CI*CO
  float* bnl = wl + CI * CO;       // 2*CI
  float* bl = bnl + 2 * CI;        // CO
  for (int i = threadIdx.x; i < CI * CO; i += 256) {
    int c = i / CO, o = i % CO;
    wl[i] = wt[o * CI + c];
  }
  for (int i = threadIdx.x; i < 2 * CI; i += 256) bnl[i] = bn[i];
  if (threadIdx.x < CO) bl[threadIdx.x] = bb[threadIdx.x];
  __syncthreads();
  int w = threadIdx.x >> 6, l = threadIdx.x & 63;
  int cb = w * COq;
  int bpb = Pos / 256;
  int b = bidl / bpb;
  int r0 = (bidl % bpb) * 256 + l * 4;
  const float* xin = yin + ((size_t)b * Pos + r0) * CI;
  v2f acc[4][COq2];
#pragma unroll
  for (int p = 0; p < 4; p++)
#pragma unroll
    for (int q = 0; q < COq2; q++) acc[p][q] = ((const v2f*)(bl + cb))[q];
  float4 cur[4], nxt[4];
#pragma unroll
  for (int p = 0; p < 4; p++) cur[p] = ((const float4*)(xin + p * CI))[0];
  for (int ch = 0; ch < CI; ch += 4) {
    if (ch + 4 < CI) {
#pragma unroll
      for (int p = 0; p < 4; p++) nxt[p] = ((const float4*)(xin + p * CI))[(ch >> 2) + 1];
    }
#pragma unroll
    for (int cc = 0; cc < 4; cc++) {
      int c = ch + cc;
      float scv = bnl[2 * c], shv = bnl[2 * c + 1];
      float xv0 = fmaxf(fmaf(((const float*)&cur[0])[cc], scv, shv), 0.f);
      float xv1 = fmaxf(fmaf(((const float*)&cur[1])[cc], scv, shv), 0.f);
      float xv2 = fmaxf(fmaf(((const float*)&cur[2])[cc], scv, shv), 0.f);
      float xv3 = fmaxf(fmaf(((const float*)&cur[3])[cc], scv, shv), 0.f);
      v2f x0 = {xv0, xv0}, x1 = {xv1, xv1}, x2 = {xv2, xv2}, x3 = {xv3, xv3};
      const float4* wr = (const float4*)(wl + c * CO + cb);
#pragma unroll
      for (int o4 = 0; o4 < COq / 4; o4++) {
        float4 wv = wr[o4];
        v2f w01 = {wv.x, wv.y}, w23 = {wv.z, wv.w};
        acc[0][2 * o4] = __builtin_elementwise_fma(w01, x0, acc[0][2 * o4]);
        acc[0][2 * o4 + 1] = __builtin_elementwise_fma(w23, x0, acc[0][2 * o4 + 1]);
        acc[1][2 * o4] = __builtin_elementwise_fma(w01, x1, acc[1][2 * o4]);
        acc[1][2 * o4 + 1] = __builtin_elementwise_fma(w23, x1, acc[1][2 * o4 + 1]);
        acc[2][2 * o4] = __builtin_elementwise_fma(w01, x2, acc[2][2 * o4]);
        acc[2][2 * o4 + 1] = __builtin_elementwise_fma(w23, x2, acc[2][2 * o4 + 1]);
        acc[3][2 * o4] = __builtin_elementwise_fma(w01, x3, acc[3][2 * o4]);
        acc[3][2 * o4 + 1] = __builtin_elementwise_fma(w23, x3, acc[3][2 * o4 + 1]);
      }
    }
#pragma unroll
    for (int p = 0; p < 4; p++) cur[p] = nxt[p];
  }
  if (K == 0) {
#pragma unroll
    for (int p = 0; p < 4; p++) {
      float4* yo = (float4*)(yout + ((size_t)b * Pos + r0 + p) * CO + cb);
#pragma unroll
      for (int o4 = 0; o4 < COq / 4; o4++)
        yo[o4] = make_float4(acc[p][2 * o4].x, acc[p][2 * o4].y, acc[p][2 * o4 + 1].x,
                             acc[p][2 * o4 + 1].y);
    }
  } else {
    int s = r0 / K;
    bool wrt = (K == 16) ? ((l & 3) == 3) : ((l & 7) == 7);
#pragma unroll
    for (int q = 0; q < COq2; q++) {
      v2f mx = __builtin_elementwise_max(__builtin_elementwise_max(acc[0][q], acc[1][q]),
                                         __builtin_elementwise_max(acc[2][q], acc[3][q]));
      v2f mn = __builtin_elementwise_min(__builtin_elementwise_min(acc[0][q], acc[1][q]),
                                         __builtin_elementwise_min(acc[2][q], acc[3][q]));
      mx = dpp_pkmax<0x111>(mx);
      mx = dpp_pkmax<0x112>(mx);
      if (K == 32) mx = dpp_pkmax<0x114>(mx);
      mn = dpp_pkmin<0x111>(mn);
      mn = dpp_pkmin<0x112>(mn);
      if (K == 32) mn = dpp_pkmin<0x114>(mn);
      if (wrt) {
        ymax[((size_t)b * CO + cb + 2 * q) * Sc + s] = mx.x;
        ymax[((size_t)b * CO + cb + 2 * q + 1) * Sc + s] = mx.y;
        ymin[((size_t)b * CO + cb + 2 * q) * Sc + s] = mn.x;
        ymin[((size_t)b * CO + cb + 2 * q + 1) * Sc + s] = mn.y;
      }
    }
  }
#pragma unroll
  for (int q = 0; q < COq2; q++) {
    v2f sv = acc[0][q] + acc[1][q] + acc[2][q] + acc[3][q];
    v2f sq = acc[0][q] * acc[0][q];
    sq = __builtin_elementwise_fma(acc[1][q], acc[1][q], sq);
    sq = __builtin_elementwise_fma(acc[2][q], acc[2][q], sq);
    sq = __builtin_elementwise_fma(acc[3][q], acc[3][q], sq);
    sv = dpp_sum64v2(sv);
    sq = dpp_sum64v2(sq);
    if (l == 63) {
      ((v2f*)part)[(size_t)bidl * CO + cb + 2 * q] = (v2f){sv.x, sq.x};
      ((v2f*)part)[(size_t)bidl * CO + cb + 2 * q + 1] = (v2f){sv.y, sq.y};
    }
  }
}

__global__ __launch_bounds__(256) void conv2M_kernel(
    const float* y0a, const float* w1a, const float* b1a, const float* bn1a, float* y1a,
    float* part0, int Pos0,
    const float* y0b, const float* w1b, const float* b1b, const float* bn1b, float* y1b,
    float* part1, int Pos1, int split) {
  __shared__ alignas(16) char smemc[25472];
  if ((int)blockIdx.x < split)
    convB_body<64, 64, 0>(smemc, blockIdx.x, y0a, w1a, b1a, bn1a, y1a, nullptr, nullptr, part0, Pos0);
  else
    convB_body<64, 96, 0>(smemc, blockIdx.x - split, y0b, w1b, b1b, bn1b, y1b, nullptr, nullptr, part1, Pos1);
}

__global__ __launch_bounds__(256) void conv3M_kernel(
    const float* y1a, const float* w2a, const float* b2a, const float* bn2a, float* ymax0,
    float* ymin0, float* part0, int Pos0,
    const float* y1b, const float* w2b, const float* b2b, const float* bn2b, float* ymax1,
    float* ymin1, float* part1, int Pos1, int split) {
  __shared__ alignas(16) char smemc[50432];
  if ((int)blockIdx.x < split)
    convB_body<64, 128, 16>(smemc, blockIdx.x, y1a, w2a, b2a, bn2a, nullptr, ymax0, ymin0, part0, Pos0);
  else
    convB_body<96, 128, 32>(smemc, blockIdx.x - split, y1b, w2b, b2b, bn2b, nullptr, ymax1, ymin1, part1, Pos1);
}

// ------- bnfin3 fused with finout (merged) -------
__global__ __launch_bounds__(256) void bnfin3fM_kernel(
    const float* part0, const float* g0, const float* be0, const float* ymax0,
    const float* ymin0, int nblk0, float inv0, int coff0,
    const float* part1, const float* g1, const float* be1, const float* ymax1,
    const float* ymin1, int nblk1, float inv1, int coff1,
    float* out1, int split) {
  constexpr int C = 128;
  const float* part; const float* g; const float* be; const float* ymaxp; const float* yminp;
  int nblk, c, coff; float invcnt;
  if ((int)blockIdx.x < split) {
    part = part0; g = g0; be = be0; ymaxp = ymax0; yminp = ymin0;
    nblk = nblk0; invcnt = inv0; coff = coff0; c = blockIdx.x;
  } else {
    part = part1; g = g1; be = be1; ymaxp = ymax1; yminp = ymin1;
    nblk = nblk1; invcnt = inv1; coff = coff1; c = blockIdx.x - split;
  }
  v2f sq = (v2f){0.f, 0.f};
  for (int i = threadIdx.x; i < nblk; i += 256) sq += ((const v2f*)part)[(size_t)i * C + c];
  sq = dpp_sum64v2(sq);
  __shared__ v2f ls[4];
  __shared__ float bnc[2];
  int w = threadIdx.x >> 6;
  if ((threadIdx.x & 63) == 63) ls[w] = sq;
  __syncthreads();
  if (threadIdx.x == 0) {
    v2f tt = ls[0] + ls[1] + ls[2] + ls[3];
    float m = tt.x * invcnt;
    float v = tt.y * invcnt - m * m;
    float sc = g[c] / sqrtf(v + BN_EPS);
    bnc[0] = sc;
    bnc[1] = fmaf(-m, sc, be[c]);
  }
  __syncthreads();
  float sc = bnc[0], sh = bnc[1];
  const float* src = (sc >= 0.f) ? ymaxp : yminp;  // ReLU∘affine monotone; max over k
#pragma unroll
  for (int k = 0; k < 32; k++) {
    int i = k * 256 + threadIdx.x;  // 8 batches * 1024 s
    int b = i >> 10, s = i & 1023;
    float v = src[((size_t)b * C + c) * Sc + s];
    out1[((size_t)b * 256 + coff + c) * Sc + s] = fmaxf(fmaf(v, sc, sh), 0.f);
  }
}

extern "C" void kernel_launch(void* const* d_in, const int* in_sizes, int n_in,
                              void* d_out, int out_size, void* d_ws, size_t ws_size,
                              hipStream_t stream) {
  const float* xyz = (const float*)d_in[0];
  const float* pts = (const float*)d_in[1];
  float* ws = (float*)d_ws;
  float* out0 = (float*)d_out;
  float* out1 = out0 + Bc * 3 * Sc;

  float4* xyzT = (float4*)(ws + 0);
  float4* nx = (float4*)(ws + 262144);
  int* knnp = (int*)(ws + 294912);
  float* P0 = ws + 557056;

  const float* d2 = (const float*)d_in[2];    // w0_0
  const float* d3 = (const float*)d_in[3];    // b0_0
  const float* d4 = (const float*)d_in[4];    // g0_0
  const float* d5 = (const float*)d_in[5];    // be0_0
  const float* d6 = (const float*)d_in[6];    // w0_1
  const float* d7 = (const float*)d_in[7];
  const float* d8 = (const float*)d_in[8];
  const float* d9 = (const float*)d_in[9];
  const float* d10 = (const float*)d_in[10];  // w0_2
  const float* d11 = (const float*)d_in[11];
  const float* d12 = (const float*)d_in[12];
  const float* d13 = (const float*)d_in[13];
  const float* d14 = (const float*)d_in[14];  // w1_0
  const float* d15 = (const float*)d_in[15];
  const float* d16 = (const float*)d_in[16];
  const float* d17 = (const float*)d_in[17];
  const float* d18 = (const float*)d_in[18];  // w1_1
  const float* d19 = (const float*)d_in[19];
  const float* d20 = (const float*)d_in[20];
  const float* d21 = (const float*)d_in[21];
  const float* d22 = (const float*)d_in[22];  // w1_2
  const float* d23 = (const float*)d_in[23];
  const float* d24 = (const float*)d_in[24];
  const float* d25 = (const float*)d_in[25];

  float inv0 = 1.f / (float)(Bc * 16384);
  float inv1 = 1.f / (float)(Bc * 32768);

  bool merged = ws_size >= (size_t)72254464 * 4;
  if (merged) {
    // disjoint per-branch buffers: both branch pipelines run fused per stage
    float* P1 = ws + 4751360;
    float* y00 = ws + 8945664;
    float* y01 = ws + 17334272;
    float* y10 = ws + 34111488;
    float* y11 = ws + 42500096;
    float* ymax0 = ws + 67665920;
    float* ymin0 = ws + 68714496;
    float* ymax1 = ws + 69763072;
    float* ymin1 = ws + 70811648;
    float* part0 = ws + 71860224;
    float* part1 = ws + 71991296;
    float* bns = ws + 72253440;
    float* bn10 = bns, *bn11 = bns + 256, *bn20 = bns + 512, *bn21 = bns + 768;

    mega_kernel<<<392, 512, 0, stream>>>(xyz, pts, d2, d3, d14, d15, xyzT, nx, out0, P0, P1);
    knn_kernel<<<1024, 256, 0, stream>>>(xyzT, nx, knnp);
    conv1M_kernel<<<1536, 256, 0, stream>>>(xyzT, nx, knnp, P0, d2, y00, part0, 16384, P1, d14,
                                            y01, part1, 32768, 512);
    bnfinM_kernel<<<128, 256, 0, stream>>>(part0, d4, d5, bn10, 64, 512, inv0, part1, d16, d17,
                                           bn11, 64, 1024, inv1, 64);
    conv2M_kernel<<<1536, 256, 0, stream>>>(y00, d6, d7, bn10, y10, part0, 16384, y01, d18, d19,
                                            bn11, y11, part1, 32768, 512);
    bnfinM_kernel<<<160, 256, 0, stream>>>(part0, d8, d9, bn20, 64, 512, inv0, part1, d20, d21,
                                           bn21, 96, 1024, inv1, 64);
    conv3M_kernel<<<1536, 256, 0, stream>>>(y10, d10, d11, bn20, ymax0, ymin0, part0, 16384, y11,
                                            d22, d23, bn21, ymax1, ymin1, part1, 32768, 512);
    bnfin3fM_kernel<<<256, 256, 0, stream>>>(part0, d12, d13, ymax0, ymin0, 512, inv0, 0, part1,
                                             d24, d25, ymax1, ymin1, 1024, inv1, 128, out1, 128);
  } else {
    // fallback: proven 196MB serial layout (r11), same kernels via split routing
    float* y0 = ws + 4751360;
    float* y1 = ws + 21528576;
    float* P1 = ws + 29917184;  // aliases y1 tail; clobbered only by conv2-br1
    float* ymax = ws + 46694400;
    float* ymin = ws + 47742976;
    float* part = ws + 48791552;
    float* bn1 = ws + 49053696;
    float* bn2 = ws + 49053824;

    mega_kernel<<<392, 512, 0, stream>>>(xyz, pts, d2, d3, d14, d15, xyzT, nx, out0, P0, P1);
    knn_kernel<<<1024, 256, 0, stream>>>(xyzT, nx, knnp);

    // branch 0 (K=16): route all blocks to slot0
    conv1M_kernel<<<512, 256, 0, stream>>>(xyzT, nx, knnp, P0, d2, y0, part, 16384, P0, d2, y0,
                                           part, 16384, 512);
    bnfinM_kernel<<<64, 256, 0, stream>>>(part, d4, d5, bn1, 64, 512, inv0, part, d4, d5, bn1, 64,
                                          512, inv0, 64);
    conv2M_kernel<<<512, 256, 0, stream>>>(y0, d6, d7, bn1, y1, part, 16384, y0, d6, d7, bn1, y1,
                                           part, 16384, 512);
    bnfinM_kernel<<<64, 256, 0, stream>>>(part, d8, d9, bn2, 64, 512, inv0, part, d8, d9, bn2, 64,
                                          512, inv0, 64);
    conv3M_kernel<<<512, 256, 0, stream>>>(y1, d10, d11, bn2, ymax, ymin, part, 16384, y1, d10,
                                           d11, bn2, ymax, ymin, part, 16384, 512);
    bnfin3fM_kernel<<<128, 256, 0, stream>>>(part, d12, d13, ymax, ymin, 512, inv0, 0, part, d12,
                                             d13, ymax, ymin, 512, inv0, 0, out1, 128);

    // branch 1 (K=32): route all blocks to slot1
    conv1M_kernel<<<1024, 256, 0, stream>>>(xyzT, nx, knnp, P1, d14, y0, part, 32768, P1, d14, y0,
                                            part, 32768, 0);
    bnfinM_kernel<<<64, 256, 0, stream>>>(part, d16, d17, bn1, 64, 1024, inv1, part, d16, d17,
                                          bn1, 64, 1024, inv1, 0);
    conv2M_kernel<<<1024, 256, 0, stream>>>(y0, d18, d19, bn1, y1, part, 32768, y0, d18, d19, bn1,
                                            y1, part, 32768, 0);
    bnfinM_kernel<<<96, 256, 0, stream>>>(part, d20, d21, bn2, 96, 1024, inv1, part, d20, d21,
                                          bn2, 96, 1024, inv1, 0);
    conv3M_kernel<<<1024, 256, 0, stream>>>(y1, d22, d23, bn2, ymax, ymin, part, 32768, y1, d22,
                                            d23, bn2, ymax, ymin, part, 32768, 0);
    bnfin3fM_kernel<<<128, 256, 0, stream>>>(part, d24, d25, ymax, ymin, 1024, inv1, 128, part,
                                             d24, d25, ymax, ymin, 1024, inv1, 128, out1, 0);
  }
  (void)in_sizes; (void)n_in; (void)out_size; (void)ws_size;
}

// Round 13
// 1461.867 us; speedup vs baseline: 1.0629x; 1.0629x over previous
//
#include <hip/hip_runtime.h>
#include <math.h>

#define BN_EPS 1e-5f
constexpr int Bc = 8, Nc = 8192, Sc = 1024, CINc = 64;

typedef float v2f __attribute__((ext_vector_type(2)));

// ---------------- DPP helpers ----------------
template <int CTRL, int RMASK>
__device__ __forceinline__ unsigned long long dpp_maxu64(unsigned long long k) {
  int lo = (int)(unsigned)k, hi = (int)(unsigned)(k >> 32);
  int olo = __builtin_amdgcn_update_dpp(lo, lo, CTRL, RMASK, 0xF, false);
  int ohi = __builtin_amdgcn_update_dpp(hi, hi, CTRL, RMASK, 0xF, false);
  unsigned long long ok = ((unsigned long long)(unsigned)ohi << 32) | (unsigned)olo;
  return ok > k ? ok : k;
}
template <int CTRL, int RMASK>
__device__ __forceinline__ v2f dpp_sumstep2(v2f v) {
  int olo = __builtin_amdgcn_update_dpp(0, __float_as_int(v.x), CTRL, RMASK, 0xF, false);
  int ohi = __builtin_amdgcn_update_dpp(0, __float_as_int(v.y), CTRL, RMASK, 0xF, false);
  v2f o = {__int_as_float(olo), __int_as_float(ohi)};
  return v + o;
}
__device__ __forceinline__ v2f dpp_sum64v2(v2f v) {
  v = dpp_sumstep2<0x111, 0xF>(v);
  v = dpp_sumstep2<0x112, 0xF>(v);
  v = dpp_sumstep2<0x114, 0xF>(v);
  v = dpp_sumstep2<0x118, 0xF>(v);
  v = dpp_sumstep2<0x142, 0xA>(v);
  v = dpp_sumstep2<0x143, 0xC>(v);
  return v;  // lane63 holds total
}
template <int CTRL>
__device__ __forceinline__ v2f dpp_pkmax(v2f v) {
  int ox = __builtin_amdgcn_update_dpp(__float_as_int(v.x), __float_as_int(v.x), CTRL, 0xF, 0xF, false);
  int oy = __builtin_amdgcn_update_dpp(__float_as_int(v.y), __float_as_int(v.y), CTRL, 0xF, 0xF, false);
  v2f o = {__int_as_float(ox), __int_as_float(oy)};
  return __builtin_elementwise_max(v, o);
}
template <int CTRL>
__device__ __forceinline__ v2f dpp_pkmin(v2f v) {
  int ox = __builtin_amdgcn_update_dpp(__float_as_int(v.x), __float_as_int(v.x), CTRL, 0xF, 0xF, false);
  int oy = __builtin_amdgcn_update_dpp(__float_as_int(v.y), __float_as_int(v.y), CTRL, 0xF, 0xF, false);
  v2f o = {__int_as_float(ox), __int_as_float(oy)};
  return __builtin_elementwise_min(v, o);
}

// ---------------- shared pproj body (P[n][64] = W_pts . points + bias) ----------------
__device__ __forceinline__ void pproj_body(int i, const float* __restrict__ pts,
                                           const float* __restrict__ wl,
                                           const float* __restrict__ bl,
                                           float* __restrict__ P) {
  int b = i >> 13, n = i & 8191;
  const float* pb = pts + (size_t)b * CINc * Nc + n;
  v2f acc[32];
  const v2f* bl2 = (const v2f*)bl;
#pragma unroll
  for (int o2 = 0; o2 < 32; o2++) acc[o2] = bl2[o2];
  for (int c = 0; c < CINc; c++) {
    float xv = pb[(size_t)c * Nc];
    v2f xv2 = {xv, xv};
    const v2f* wr = (const v2f*)(wl + c * 64);
#pragma unroll
    for (int o2 = 0; o2 < 32; o2++) acc[o2] = __builtin_elementwise_fma(wr[o2], xv2, acc[o2]);
  }
  float4* Pn = (float4*)(P + (size_t)i * 64);
#pragma unroll
  for (int o4 = 0; o4 < 16; o4++)
    Pn[o4] = make_float4(acc[2 * o4].x, acc[2 * o4].y, acc[2 * o4 + 1].x, acc[2 * o4 + 1].y);
}

// ------- mega: blocks 0-7 fps (512t, pk dist + inline argmax), 8-135 xyzt,
//         136-263 pproj0, 264-391 pproj1
__global__ __launch_bounds__(512) void mega_kernel(const float* __restrict__ xyz,
                                                   const float* __restrict__ pts,
                                                   const float* __restrict__ w00,
                                                   const float* __restrict__ b00,
                                                   const float* __restrict__ w10,
                                                   const float* __restrict__ b10,
                                                   float4* __restrict__ xyzT,
                                                   float4* __restrict__ nx,
                                                   float* __restrict__ out0,
                                                   float* __restrict__ P0,
                                                   float* __restrict__ P1) {
  __shared__ alignas(16) char smemc[102528];
  int bid = blockIdx.x, t = threadIdx.x;
  if (bid < 8) {
    float* xs = (float*)smemc;
    float* ys = xs + Nc;
    float* zs = ys + Nc;
    int* idxs = (int*)(smemc + 98304);
    unsigned long long* red = (unsigned long long*)(smemc + 102400);  // [2][8]
    const float* xb = xyz + (size_t)bid * 3 * Nc;
    v2f px[8], py[8], pz[8], dd[8];
#pragma unroll
    for (int j = 0; j < 8; j++) {
      int n0 = (2 * j) * 512 + t, n1 = n0 + 512;
      float x0 = xb[n0], y0 = xb[Nc + n0], z0 = xb[2 * Nc + n0];
      float x1 = xb[n1], y1 = xb[Nc + n1], z1 = xb[2 * Nc + n1];
      xs[n0] = x0; ys[n0] = y0; zs[n0] = z0;
      xs[n1] = x1; ys[n1] = y1; zs[n1] = z1;
      px[j] = (v2f){x0, x1}; py[j] = (v2f){y0, y1}; pz[j] = (v2f){z0, z1};
      dd[j] = (v2f){1e10f, 1e10f};
    }
    int w = t >> 6;
    __syncthreads();
    int curIdx = 0;
    for (int i = 0; i < Sc; i++) {
      float cx = xs[curIdx], cy = ys[curIdx], cz = zs[curIdx];  // LDS broadcast
      if (t == 0) idxs[i] = curIdx;
      v2f cx2 = (v2f){cx, cx}, cy2 = (v2f){cy, cy}, cz2 = (v2f){cz, cz};
      float bd = -1.f;
      int bnx = 0;
#pragma unroll
      for (int j = 0; j < 8; j++) {
        v2f dx = px[j] - cx2, dy = py[j] - cy2, dz = pz[j] - cz2;
        v2f d = __builtin_elementwise_fma(dz, dz, __builtin_elementwise_fma(dy, dy, dx * dx));
        d = __builtin_elementwise_min(dd[j], d);
        dd[j] = d;
        // ascending n per lane; strict >: first index wins (jnp.argmax)
        if (d.x > bd) { bd = d.x; bnx = (2 * j) * 512 + t; }
        if (d.y > bd) { bd = d.y; bnx = (2 * j) * 512 + t + 512; }
      }
      unsigned long long key =
          ((unsigned long long)__float_as_uint(bd) << 32) | (unsigned)(~bnx);
      key = dpp_maxu64<0x111, 0xF>(key);
      key = dpp_maxu64<0x112, 0xF>(key);
      key = dpp_maxu64<0x114, 0xF>(key);
      key = dpp_maxu64<0x118, 0xF>(key);
      key = dpp_maxu64<0x142, 0xA>(key);
      key = dpp_maxu64<0x143, 0xC>(key);
      if ((t & 63) == 63) red[(i & 1) * 8 + w] = key;
      __syncthreads();
      const unsigned long long* rr = red + (i & 1) * 8;
      unsigned long long m01 = rr[0] > rr[1] ? rr[0] : rr[1];
      unsigned long long m23 = rr[2] > rr[3] ? rr[2] : rr[3];
      unsigned long long m45 = rr[4] > rr[5] ? rr[4] : rr[5];
      unsigned long long m67 = rr[6] > rr[7] ? rr[6] : rr[7];
      unsigned long long m03 = m01 > m23 ? m01 : m23;
      unsigned long long m47 = m45 > m67 ? m45 : m67;
      unsigned long long k2 = m03 > m47 ? m03 : m47;
      curIdx = (int)(~(unsigned)(k2 & 0xFFFFFFFFull));
    }
    __syncthreads();
    for (int i2 = t; i2 < Sc; i2 += 512) {
      int idx = idxs[i2];
      float x = xs[idx], y = ys[idx], z = zs[idx];
      nx[bid * Sc + i2] = make_float4(x, y, z, fmaf(z, z, fmaf(y, y, x * x)));
      float* ob = out0 + (size_t)bid * 3 * Sc;
      ob[i2] = x; ob[Sc + i2] = y; ob[2 * Sc + i2] = z;
    }
  } else if (bid < 136) {
    int i = (bid - 8) * 512 + t;
    int b = i >> 13, n = i & 8191;
    const float* xb = xyz + (size_t)b * 3 * Nc;
    float x = xb[n], y = xb[Nc + n], z = xb[2 * Nc + n];
    xyzT[i] = make_float4(x, y, z, fmaf(z, z, fmaf(y, y, x * x)));
  } else {
    bool second = bid >= 264;
    const float* ww = second ? w10 : w00;
    const float* bb = second ? b10 : b00;
    float* PP = second ? P1 : P0;
    float* wl = (float*)smemc;  // 64*64 floats
    float* bl = wl + 64 * 64;
    for (int i2 = t; i2 < 64 * 64; i2 += 512) {
      int c = i2 >> 6, o = i2 & 63;
      wl[i2] = ww[o * 67 + 3 + c];
    }
    if (t < 64) bl[t] = bb[t];
    __syncthreads();
    pproj_body(((bid - (second ? 264 : 136)) * 512) + t, pts, wl, bl, PP);
  }
}

// ---------------- wave-cooperative 32-NN: sorted-insertion updates ----------------
// Sorted top-32 list across each 32-lane group as u64 keys (ordered-dist<<32|idx).
// Per batch: ballot candidates beating worst; insert lowest-index-first via
// broadcast + popcount-rank + shfl_up shift; re-filter vs new worst.
__global__ __launch_bounds__(256) void knn_kernel(const float4* __restrict__ xyzT,
                                                  const float4* __restrict__ newxyz,
                                                  int* __restrict__ knn) {
  int lane = threadIdx.x & 63;
  int sub = lane >> 5;
  int l32 = lane & 31;
  int waveId = blockIdx.x * 4 + (threadIdx.x >> 6);
  int q = waveId * 2 + sub;
  int b = q >> 10;
  float4 qv = newxyz[q];
  const float4* pb = xyzT + (size_t)b * Nc;
  unsigned long long lk = ~0ull;     // sorted asc across 32-group; sentinel = max key
  unsigned long long worst = ~0ull;  // group-uniform copy of lane31's key
  for (int t0 = 0; t0 < Nc; t0 += 32) {
    float4 p = pb[t0 + l32];
    float dot = fmaf(qv.z, p.z, fmaf(qv.y, p.y, qv.x * p.x));
    float d = fmaf(-2.f, dot, qv.w + p.w);  // aa + bb - 2ab, same as reference
    unsigned fu = __float_as_uint(d);
    fu ^= (unsigned)(-(int)(fu >> 31)) | 0x80000000u;  // ordered-uint transform
    unsigned long long ck = ((unsigned long long)fu << 32) | (unsigned)(t0 + l32);
    unsigned long long bal = __ballot(ck < worst);
    unsigned mymask = (unsigned)(bal >> (sub * 32));
    while (mymask) {
      int src = __ffs(mymask) - 1;                     // lowest lane = lowest idx (stable)
      unsigned long long ckb = __shfl(ck, src, 32);    // broadcast candidate key
      unsigned long long bel = __ballot(lk < ckb);
      int cnt = __popc((unsigned)(bel >> (sub * 32))); // insertion rank
      unsigned long long up = __shfl_up(lk, 1, 32);
      lk = (l32 == cnt) ? ckb : ((l32 > cnt) ? up : lk);  // shift-insert, lane31 drops
      worst = __shfl(lk, 31, 32);
      mymask &= ~(1u << src);
      unsigned long long bal2 = __ballot(ck < worst);  // re-filter vs new worst
      mymask &= (unsigned)(bal2 >> (sub * 32));
    }
  }
  knn[(size_t)q * 32 + l32] = (int)(lk & 0xFFFFFFFFu);
}

// ---------------- conv1 body (branch-templated, shared smem carve) ----------------
template <int K>
__device__ __forceinline__ void conv1_body(char* smemc, int bidl,
                                           const float4* __restrict__ xyzT,
                                           const float4* __restrict__ nx,
                                           const int* __restrict__ knn,
                                           const float* __restrict__ P,
                                           const float* __restrict__ w0,
                                           float* __restrict__ y,
                                           float* __restrict__ part, int Pos) {
  v2f* wst = (v2f*)smemc;  // 16*64 v2f = 8192 B
  float* wx = (float*)(smemc + 8192);
  float* wy = wx + 64;
  float* wz = wy + 64;
  if (threadIdx.x < 64) {
    int o = threadIdx.x;
    wx[o] = w0[o * 67];
    wy[o] = w0[o * 67 + 1];
    wz[o] = w0[o * 67 + 2];
  }
  __syncthreads();
  int gp = bidl * 256 + threadIdx.x;
  int b = gp / Pos, r = gp % Pos;
  int s = r / K, kk = r & (K - 1);
  int n = knn[((size_t)(b * Sc + s)) * 32 + kk];
  float4 c4 = nx[b * Sc + s];
  float4 p4 = xyzT[(size_t)b * Nc + n];
  v2f dx2 = {p4.x - c4.x, p4.x - c4.x};
  v2f dy2 = {p4.y - c4.y, p4.y - c4.y};
  v2f dz2 = {p4.z - c4.z, p4.z - c4.z};
  const float4* Pn = (const float4*)(P + ((size_t)b * Nc + n) * 64);
  v2f acc[32];
#pragma unroll
  for (int o4 = 0; o4 < 16; o4++) {
    float4 v = Pn[o4];
    acc[2 * o4] = (v2f){v.x, v.y};
    acc[2 * o4 + 1] = (v2f){v.z, v.w};
  }
  const v2f* wx2 = (const v2f*)wx;
  const v2f* wy2 = (const v2f*)wy;
  const v2f* wz2 = (const v2f*)wz;
#pragma unroll
  for (int o2 = 0; o2 < 32; o2++) acc[o2] = __builtin_elementwise_fma(wx2[o2], dx2, acc[o2]);
#pragma unroll
  for (int o2 = 0; o2 < 32; o2++) acc[o2] = __builtin_elementwise_fma(wy2[o2], dy2, acc[o2]);
#pragma unroll
  for (int o2 = 0; o2 < 32; o2++) acc[o2] = __builtin_elementwise_fma(wz2[o2], dz2, acc[o2]);
  float4* yb = (float4*)(y + ((size_t)b * Pos + r) * 64);
#pragma unroll
  for (int o4 = 0; o4 < 16; o4++)
    yb[o4] = make_float4(acc[2 * o4].x, acc[2 * o4].y, acc[2 * o4 + 1].x, acc[2 * o4 + 1].y);
  int lane = threadIdx.x & 63, w = threadIdx.x >> 6;
  int row = w * 4 + (lane >> 4);
  bool lead = (lane & 15) == 15;
#pragma unroll
  for (int o2 = 0; o2 < 32; o2++) {
    float v0 = acc[o2].x, v1 = acc[o2].y;
    v2f s0 = (v2f){v0, v0 * v0};
    s0 = dpp_sumstep2<0x111, 0xF>(s0);
    s0 = dpp_sumstep2<0x112, 0xF>(s0);
    s0 = dpp_sumstep2<0x114, 0xF>(s0);
    s0 = dpp_sumstep2<0x118, 0xF>(s0);
    v2f s1 = (v2f){v1, v1 * v1};
    s1 = dpp_sumstep2<0x111, 0xF>(s1);
    s1 = dpp_sumstep2<0x112, 0xF>(s1);
    s1 = dpp_sumstep2<0x114, 0xF>(s1);
    s1 = dpp_sumstep2<0x118, 0xF>(s1);
    if (lead) { wst[row * 64 + 2 * o2] = s0; wst[row * 64 + 2 * o2 + 1] = s1; }
  }
  __syncthreads();
  if (threadIdx.x < 64) {
    int o = threadIdx.x;
    v2f sv = (v2f){0.f, 0.f};
#pragma unroll
    for (int rr = 0; rr < 16; rr++) sv += wst[rr * 64 + o];
    ((v2f*)part)[(size_t)bidl * 64 + o] = sv;
  }
}

__global__ __launch_bounds__(256) void conv1M_kernel(
    const float4* xyzT, const float4* nx, const int* knn,
    const float* P0, const float* w0a, float* y0a, float* part0, int Pos0,
    const float* P1, const float* w0b, float* y0b, float* part1, int Pos1, int split) {
  __shared__ alignas(16) char smemc[8960];
  if ((int)blockIdx.x < split)
    conv1_body<16>(smemc, blockIdx.x, xyzT, nx, knn, P0, w0a, y0a, part0, Pos0);
  else
    conv1_body<32>(smemc, blockIdx.x - split, xyzT, nx, knn, P1, w0b, y0b, part1, Pos1);
}

// ---------------- bn finalize (merged, runtime C) ----------------
__global__ __launch_bounds__(256) void bnfinM_kernel(
    const float* part0, const float* g0, const float* be0, float* bn0, int C0, int nblk0, float inv0,
    const float* part1, const float* g1, const float* be1, float* bn1, int C1, int nblk1, float inv1,
    int split) {
  const float* part; const float* g; const float* be; float* bn;
  int C, nblk, c; float invcnt;
  if ((int)blockIdx.x < split) {
    part = part0; g = g0; be = be0; bn = bn0; C = C0; nblk = nblk0; invcnt = inv0; c = blockIdx.x;
  } else {
    part = part1; g = g1; be = be1; bn = bn1; C = C1; nblk = nblk1; invcnt = inv1; c = blockIdx.x - split;
  }
  v2f sq = (v2f){0.f, 0.f};
  for (int i = threadIdx.x; i < nblk; i += 256) sq += ((const v2f*)part)[(size_t)i * C + c];
  sq = dpp_sum64v2(sq);
  __shared__ v2f ls[4];
  int w = threadIdx.x >> 6;
  if ((threadIdx.x & 63) == 63) ls[w] = sq;
  __syncthreads();
  if (threadIdx.x == 0) {
    v2f tt = ls[0] + ls[1] + ls[2] + ls[3];
    float m = tt.x * invcnt;
    float v = tt.y * invcnt - m * m;
    float sc = g[c] / sqrtf(v + BN_EPS);
    bn[c * 2] = sc;
    bn[c * 2 + 1] = fmaf(-m, sc, be[c]);
  }
}

// ---------------- convB body (shared smem carve) ----------------
template <int CI, int CO, int K>
__device__ __forceinline__ void convB_body(char* smemc, int bidl,
                                           const float* __restrict__ yin,
                                           const float* __restrict__ wt,
                                           const float* __restrict__ bb,
                                           const float* __restrict__ bn,
                                           float* __restrict__ yout,
                                           float* __restrict__ ymax,
                                           float* __restrict__ ymin,
                                           float* __restrict__ part, int Pos) {
  constexpr int COq = CO / 4;
  constexpr int COq2 = COq / 2;
  float* wl = (float*)smemc;       // CI*CO
  float* bnl = wl + CI * CO;       // 2*CI
  float* bl = bnl + 2 * CI;        // CO
  for (int i = threadIdx.x; i < CI * CO; i += 256) {
    int c = i / CO, o = i % CO;
    wl[i] = wt[o * CI + c];
  }
  for (int i = threadIdx.x; i < 2 * CI; i += 256) bnl[i] = bn[i];
  if (threadIdx.x < CO) bl[threadIdx.x] = bb[threadIdx.x];
  __syncthreads();
  int w = threadIdx.x >> 6, l = threadIdx.x & 63;
  int cb = w * COq;
  int bpb = Pos / 256;
  int b = bidl / bpb;
  int r0 = (bidl % bpb) * 256 + l * 4;
  const float* xin = yin + ((size_t)b * Pos + r0) * CI;
  v2f acc[4][COq2];
#pragma unroll
  for (int p = 0; p < 4; p++)
#pragma unroll
    for (int q = 0; q < COq2; q++) acc[p][q] = ((const v2f*)(bl + cb))[q];
  float4 cur[4], nxt[4];
#pragma unroll
  for (int p = 0; p < 4; p++) cur[p] = ((const float4*)(xin + p * CI))[0];
  for (int ch = 0; ch < CI; ch += 4) {
    if (ch + 4 < CI) {
#pragma unroll
      for (int p = 0; p < 4; p++) nxt[p] = ((const float4*)(xin + p * CI))[(ch >> 2) + 1];
    }
#pragma unroll
    for (int cc = 0; cc < 4; cc++) {
      int c = ch + cc;
      float scv = bnl[2 * c], shv = bnl[2 * c + 1];
      float xv0 = fmaxf(fmaf(((const float*)&cur[0])[cc], scv, shv), 0.f);
      float xv1 = fmaxf(fmaf(((const float*)&cur[1])[cc], scv, shv), 0.f);
      float xv2 = fmaxf(fmaf(((const float*)&cur[2])[cc], scv, shv), 0.f);
      float xv3 = fmaxf(fmaf(((const float*)&cur[3])[cc], scv, shv), 0.f);
      v2f x0 = {xv0, xv0}, x1 = {xv1, xv1}, x2 = {xv2, xv2}, x3 = {xv3, xv3};
      const float4* wr = (const float4*)(wl + c * CO + cb);
#pragma unroll
      for (int o4 = 0; o4 < COq / 4; o4++) {
        float4 wv = wr[o4];
        v2f w01 = {wv.x, wv.y}, w23 = {wv.z, wv.w};
        acc[0][2 * o4] = __builtin_elementwise_fma(w01, x0, acc[0][2 * o4]);
        acc[0][2 * o4 + 1] = __builtin_elementwise_fma(w23, x0, acc[0][2 * o4 + 1]);
        acc[1][2 * o4] = __builtin_elementwise_fma(w01, x1, acc[1][2 * o4]);
        acc[1][2 * o4 + 1] = __builtin_elementwise_fma(w23, x1, acc[1][2 * o4 + 1]);
        acc[2][2 * o4] = __builtin_elementwise_fma(w01, x2, acc[2][2 * o4]);
        acc[2][2 * o4 + 1] = __builtin_elementwise_fma(w23, x2, acc[2][2 * o4 + 1]);
        acc[3][2 * o4] = __builtin_elementwise_fma(w01, x3, acc[3][2 * o4]);
        acc[3][2 * o4 + 1] = __builtin_elementwise_fma(w23, x3, acc[3][2 * o4 + 1]);
      }
    }
#pragma unroll
    for (int p = 0; p < 4; p++) cur[p] = nxt[p];
  }
  if (K == 0) {
#pragma unroll
    for (int p = 0; p < 4; p++) {
      float4* yo = (float4*)(yout + ((size_t)b * Pos + r0 + p) * CO + cb);
#pragma unroll
      for (int o4 = 0; o4 < COq / 4; o4++)
        yo[o4] = make_float4(acc[p][2 * o4].x, acc[p][2 * o4].y, acc[p][2 * o4 + 1].x,
                             acc[p][2 * o4 + 1].y);
    }
  } else {
    int s = r0 / K;
    bool wrt = (K == 16) ? ((l & 3) == 3) : ((l & 7) == 7);
#pragma unroll
    for (int q = 0; q < COq2; q++) {
      v2f mx = __builtin_elementwise_max(__builtin_elementwise_max(acc[0][q], acc[1][q]),
                                         __builtin_elementwise_max(acc[2][q], acc[3][q]));
      v2f mn = __builtin_elementwise_min(__builtin_elementwise_min(acc[0][q], acc[1][q]),
                                         __builtin_elementwise_min(acc[2][q], acc[3][q]));
      mx = dpp_pkmax<0x111>(mx);
      mx = dpp_pkmax<0x112>(mx);
      if (K == 32) mx = dpp_pkmax<0x114>(mx);
      mn = dpp_pkmin<0x111>(mn);
      mn = dpp_pkmin<0x112>(mn);
      if (K == 32) mn = dpp_pkmin<0x114>(mn);
      if (wrt) {
        ymax[((size_t)b * CO + cb + 2 * q) * Sc + s] = mx.x;
        ymax[((size_t)b * CO + cb + 2 * q + 1) * Sc + s] = mx.y;
        ymin[((size_t)b * CO + cb + 2 * q) * Sc + s] = mn.x;
        ymin[((size_t)b * CO + cb + 2 * q + 1) * Sc + s] = mn.y;
      }
    }
  }
#pragma unroll
  for (int q = 0; q < COq2; q++) {
    v2f sv = acc[0][q] + acc[1][q] + acc[2][q] + acc[3][q];
    v2f sq = acc[0][q] * acc[0][q];
    sq = __builtin_elementwise_fma(acc[1][q], acc[1][q], sq);
    sq = __builtin_elementwise_fma(acc[2][q], acc[2][q], sq);
    sq = __builtin_elementwise_fma(acc[3][q], acc[3][q], sq);
    sv = dpp_sum64v2(sv);
    sq = dpp_sum64v2(sq);
    if (l == 63) {
      ((v2f*)part)[(size_t)bidl * CO + cb + 2 * q] = (v2f){sv.x, sq.x};
      ((v2f*)part)[(size_t)bidl * CO + cb + 2 * q + 1] = (v2f){sv.y, sq.y};
    }
  }
}

__global__ __launch_bounds__(256) void conv2M_kernel(
    const float* y0a, const float* w1a, const float* b1a, const float* bn1a, float* y1a,
    float* part0, int Pos0,
    const float* y0b, const float* w1b, const float* b1b, const float* bn1b, float* y1b,
    float* part1, int Pos1, int split) {
  __shared__ alignas(16) char smemc[25472];
  if ((int)blockIdx.x < split)
    convB_body<64, 64, 0>(smemc, blockIdx.x, y0a, w1a, b1a, bn1a, y1a, nullptr, nullptr, part0, Pos0);
  else
    convB_body<64, 96, 0>(smemc, blockIdx.x - split, y0b, w1b, b1b, bn1b, y1b, nullptr, nullptr, part1, Pos1);
}

__global__ __launch_bounds__(256) void conv3M_kernel(
    const float* y1a, const float* w2a, const float* b2a, const float* bn2a, float* ymax0,
    float* ymin0, float* part0, int Pos0,
    const float* y1b, const float* w2b, const float* b2b, const float* bn2b, float* ymax1,
    float* ymin1, float* part1, int Pos1, int split) {
  __shared__ alignas(16) char smemc[50432];
  if ((int)blockIdx.x < split)
    convB_body<64, 128, 16>(smemc, blockIdx.x, y1a, w2a, b2a, bn2a, nullptr, ymax0, ymin0, part0, Pos0);
  else
    convB_body<96, 128, 32>(smemc, blockIdx.x - split, y1b, w2b, b2b, bn2b, nullptr, ymax1, ymin1, part1, Pos1);
}

// ------- bnfin3 fused with finout (merged) -------
__global__ __launch_bounds__(256) void bnfin3fM_kernel(
    const float* part0, const float* g0, const float* be0, const float* ymax0,
    const float* ymin0, int nblk0, float inv0, int coff0,
    const float* part1, const float* g1, const float* be1, const float* ymax1,
    const float* ymin1, int nblk1, float inv1, int coff1,
    float* out1, int split) {
  constexpr int C = 128;
  const float* part; const float* g; const float* be; const float* ymaxp; const float* yminp;
  int nblk, c, coff; float invcnt;
  if ((int)blockIdx.x < split) {
    part = part0; g = g0; be = be0; ymaxp = ymax0; yminp = ymin0;
    nblk = nblk0; invcnt = inv0; coff = coff0; c = blockIdx.x;
  } else {
    part = part1; g = g1; be = be1; ymaxp = ymax1; yminp = ymin1;
    nblk = nblk1; invcnt = inv1; coff = coff1; c = blockIdx.x - split;
  }
  v2f sq = (v2f){0.f, 0.f};
  for (int i = threadIdx.x; i < nblk; i += 256) sq += ((const v2f*)part)[(size_t)i * C + c];
  sq = dpp_sum64v2(sq);
  __shared__ v2f ls[4];
  __shared__ float bnc[2];
  int w = threadIdx.x >> 6;
  if ((threadIdx.x & 63) == 63) ls[w] = sq;
  __syncthreads();
  if (threadIdx.x == 0) {
    v2f tt = ls[0] + ls[1] + ls[2] + ls[3];
    float m = tt.x * invcnt;
    float v = tt.y * invcnt - m * m;
    float sc = g[c] / sqrtf(v + BN_EPS);
    bnc[0] = sc;
    bnc[1] = fmaf(-m, sc, be[c]);
  }
  __syncthreads();
  float sc = bnc[0], sh = bnc[1];
  const float* src = (sc >= 0.f) ? ymaxp : yminp;  // ReLU∘affine monotone; max over k
#pragma unroll
  for (int k = 0; k < 32; k++) {
    int i = k * 256 + threadIdx.x;  // 8 batches * 1024 s
    int b = i >> 10, s = i & 1023;
    float v = src[((size_t)b * C + c) * Sc + s];
    out1[((size_t)b * 256 + coff + c) * Sc + s] = fmaxf(fmaf(v, sc, sh), 0.f);
  }
}

extern "C" void kernel_launch(void* const* d_in, const int* in_sizes, int n_in,
                              void* d_out, int out_size, void* d_ws, size_t ws_size,
                              hipStream_t stream) {
  const float* xyz = (const float*)d_in[0];
  const float* pts = (const float*)d_in[1];
  float* ws = (float*)d_ws;
  float* out0 = (float*)d_out;
  float* out1 = out0 + Bc * 3 * Sc;

  float4* xyzT = (float4*)(ws + 0);
  float4* nx = (float4*)(ws + 262144);
  int* knnp = (int*)(ws + 294912);
  float* P0 = ws + 557056;

  const float* d2 = (const float*)d_in[2];
  const float* d3 = (const float*)d_in[3];
  const float* d4 = (const float*)d_in[4];
  const float* d5 = (const float*)d_in[5];
  const float* d6 = (const float*)d_in[6];
  const float* d7 = (const float*)d_in[7];
  const float* d8 = (const float*)d_in[8];
  const float* d9 = (const float*)d_in[9];
  const float* d10 = (const float*)d_in[10];
  const float* d11 = (const float*)d_in[11];
  const float* d12 = (const float*)d_in[12];
  const float* d13 = (const float*)d_in[13];
  const float* d14 = (const float*)d_in[14];
  const float* d15 = (const float*)d_in[15];
  const float* d16 = (const float*)d_in[16];
  const float* d17 = (const float*)d_in[17];
  const float* d18 = (const float*)d_in[18];
  const float* d19 = (const float*)d_in[19];
  const float* d20 = (const float*)d_in[20];
  const float* d21 = (const float*)d_in[21];
  const float* d22 = (const float*)d_in[22];
  const float* d23 = (const float*)d_in[23];
  const float* d24 = (const float*)d_in[24];
  const float* d25 = (const float*)d_in[25];

  float inv0 = 1.f / (float)(Bc * 16384);
  float inv1 = 1.f / (float)(Bc * 32768);

  bool merged = ws_size >= (size_t)72254464 * 4;
  if (merged) {
    float* P1 = ws + 4751360;
    float* y00 = ws + 8945664;
    float* y01 = ws + 17334272;
    float* y10 = ws + 34111488;
    float* y11 = ws + 42500096;
    float* ymax0 = ws + 67665920;
    float* ymin0 = ws + 68714496;
    float* ymax1 = ws + 69763072;
    float* ymin1 = ws + 70811648;
    float* part0 = ws + 71860224;
    float* part1 = ws + 71991296;
    float* bns = ws + 72253440;
    float* bn10 = bns, *bn11 = bns + 256, *bn20 = bns + 512, *bn21 = bns + 768;

    mega_kernel<<<392, 512, 0, stream>>>(xyz, pts, d2, d3, d14, d15, xyzT, nx, out0, P0, P1);
    knn_kernel<<<1024, 256, 0, stream>>>(xyzT, nx, knnp);
    conv1M_kernel<<<1536, 256, 0, stream>>>(xyzT, nx, knnp, P0, d2, y00, part0, 16384, P1, d14,
                                            y01, part1, 32768, 512);
    bnfinM_kernel<<<128, 256, 0, stream>>>(part0, d4, d5, bn10, 64, 512, inv0, part1, d16, d17,
                                           bn11, 64, 1024, inv1, 64);
    conv2M_kernel<<<1536, 256, 0, stream>>>(y00, d6, d7, bn10, y10, part0, 16384, y01, d18, d19,
                                            bn11, y11, part1, 32768, 512);
    bnfinM_kernel<<<160, 256, 0, stream>>>(part0, d8, d9, bn20, 64, 512, inv0, part1, d20, d21,
                                           bn21, 96, 1024, inv1, 64);
    conv3M_kernel<<<1536, 256, 0, stream>>>(y10, d10, d11, bn20, ymax0, ymin0, part0, 16384, y11,
                                            d22, d23, bn21, ymax1, ymin1, part1, 32768, 512);
    bnfin3fM_kernel<<<256, 256, 0, stream>>>(part0, d12, d13, ymax0, ymin0, 512, inv0, 0, part1,
                                             d24, d25, ymax1, ymin1, 1024, inv1, 128, out1, 128);
  } else {
    float* y0 = ws + 4751360;
    float* y1 = ws + 21528576;
    float* P1 = ws + 29917184;  // aliases y1 tail; clobbered only by conv2-br1
    float* ymax = ws + 46694400;
    float* ymin = ws + 47742976;
    float* part = ws + 48791552;
    float* bn1 = ws + 49053696;
    float* bn2 = ws + 49053824;

    mega_kernel<<<392, 512, 0, stream>>>(xyz, pts, d2, d3, d14, d15, xyzT, nx, out0, P0, P1);
    knn_kernel<<<1024, 256, 0, stream>>>(xyzT, nx, knnp);

    conv1M_kernel<<<512, 256, 0, stream>>>(xyzT, nx, knnp, P0, d2, y0, part, 16384, P0, d2, y0,
                                           part, 16384, 512);
    bnfinM_kernel<<<64, 256, 0, stream>>>(part, d4, d5, bn1, 64, 512, inv0, part, d4, d5, bn1, 64,
                                          512, inv0, 64);
    conv2M_kernel<<<512, 256, 0, stream>>>(y0, d6, d7, bn1, y1, part, 16384, y0, d6, d7, bn1, y1,
                                           part, 16384, 512);
    bnfinM_kernel<<<64, 256, 0, stream>>>(part, d8, d9, bn2, 64, 512, inv0, part, d8, d9, bn2, 64,
                                          512, inv0, 64);
    conv3M_kernel<<<512, 256, 0, stream>>>(y1, d10, d11, bn2, ymax, ymin, part, 16384, y1, d10,
                                           d11, bn2, ymax, ymin, part, 16384, 512);
    bnfin3fM_kernel<<<128, 256, 0, stream>>>(part, d12, d13, ymax, ymin, 512, inv0, 0, part, d12,
                                             d13, ymax, ymin, 512, inv0, 0, out1, 128);

    conv1M_kernel<<<1024, 256, 0, stream>>>(xyzT, nx, knnp, P1, d14, y0, part, 32768, P1, d14, y0,
                                            part, 32768, 0);
    bnfinM_kernel<<<64, 256, 0, stream>>>(part, d16, d17, bn1, 64, 1024, inv1, part, d16, d17,
                                          bn1, 64, 1024, inv1, 0);
    conv2M_kernel<<<1024, 256, 0, stream>>>(y0, d18, d19, bn1, y1, part, 32768, y0, d18, d19, bn1,
                                            y1, part, 32768, 0);
    bnfinM_kernel<<<96, 256, 0, stream>>>(part, d20, d21, bn2, 96, 1024, inv1, part, d20, d21,
                                          bn2, 96, 1024, inv1, 0);
    conv3M_kernel<<<1024, 256, 0, stream>>>(y1, d22, d23, bn2, ymax, ymin, part, 32768, y1, d22,
                                            d23, bn2, ymax, ymin, part, 32768, 0);
    bnfin3fM_kernel<<<128, 256, 0, stream>>>(part, d24, d25, ymax, ymin, 1024, inv1, 128, part,
                                             d24, d25, ymax, ymin, 1024, inv1, 128, out1, 0);
  }
  (void)in_sizes; (void)n_in; (void)out_size; (void)ws_size;
}

// Round 14
// 1387.388 us; speedup vs baseline: 1.1199x; 1.0537x over previous
//
#include <hip/hip_runtime.h>
#include <math.h>

#define BN_EPS 1e-5f
constexpr int Bc = 8, Nc = 8192, Sc = 1024, CINc = 64;

typedef float v2f __attribute__((ext_vector_type(2)));

// ---------------- DPP helpers ----------------
template <int CTRL, int RMASK>
__device__ __forceinline__ unsigned long long dpp_maxu64(unsigned long long k) {
  int lo = (int)(unsigned)k, hi = (int)(unsigned)(k >> 32);
  int olo = __builtin_amdgcn_update_dpp(lo, lo, CTRL, RMASK, 0xF, false);
  int ohi = __builtin_amdgcn_update_dpp(hi, hi, CTRL, RMASK, 0xF, false);
  unsigned long long ok = ((unsigned long long)(unsigned)ohi << 32) | (unsigned)olo;
  return ok > k ? ok : k;
}
template <int CTRL, int RMASK>
__device__ __forceinline__ v2f dpp_sumstep2(v2f v) {
  int olo = __builtin_amdgcn_update_dpp(0, __float_as_int(v.x), CTRL, RMASK, 0xF, false);
  int ohi = __builtin_amdgcn_update_dpp(0, __float_as_int(v.y), CTRL, RMASK, 0xF, false);
  v2f o = {__int_as_float(olo), __int_as_float(ohi)};
  return v + o;
}
__device__ __forceinline__ v2f dpp_sum64v2(v2f v) {
  v = dpp_sumstep2<0x111, 0xF>(v);
  v = dpp_sumstep2<0x112, 0xF>(v);
  v = dpp_sumstep2<0x114, 0xF>(v);
  v = dpp_sumstep2<0x118, 0xF>(v);
  v = dpp_sumstep2<0x142, 0xA>(v);
  v = dpp_sumstep2<0x143, 0xC>(v);
  return v;  // lane63 holds total
}
template <int CTRL>
__device__ __forceinline__ v2f dpp_pkmax(v2f v) {
  int ox = __builtin_amdgcn_update_dpp(__float_as_int(v.x), __float_as_int(v.x), CTRL, 0xF, 0xF, false);
  int oy = __builtin_amdgcn_update_dpp(__float_as_int(v.y), __float_as_int(v.y), CTRL, 0xF, 0xF, false);
  v2f o = {__int_as_float(ox), __int_as_float(oy)};
  return __builtin_elementwise_max(v, o);
}
template <int CTRL>
__device__ __forceinline__ v2f dpp_pkmin(v2f v) {
  int ox = __builtin_amdgcn_update_dpp(__float_as_int(v.x), __float_as_int(v.x), CTRL, 0xF, 0xF, false);
  int oy = __builtin_amdgcn_update_dpp(__float_as_int(v.y), __float_as_int(v.y), CTRL, 0xF, 0xF, false);
  v2f o = {__int_as_float(ox), __int_as_float(oy)};
  return __builtin_elementwise_min(v, o);
}

// ---------------- shared pproj body (P[n][64] = W_pts . points + bias) ----------------
__device__ __forceinline__ void pproj_body(int i, const float* __restrict__ pts,
                                           const float* __restrict__ wl,
                                           const float* __restrict__ bl,
                                           float* __restrict__ P) {
  int b = i >> 13, n = i & 8191;
  const float* pb = pts + (size_t)b * CINc * Nc + n;
  v2f acc[32];
  const v2f* bl2 = (const v2f*)bl;
#pragma unroll
  for (int o2 = 0; o2 < 32; o2++) acc[o2] = bl2[o2];
  for (int c = 0; c < CINc; c++) {
    float xv = pb[(size_t)c * Nc];
    v2f xv2 = {xv, xv};
    const v2f* wr = (const v2f*)(wl + c * 64);
#pragma unroll
    for (int o2 = 0; o2 < 32; o2++) acc[o2] = __builtin_elementwise_fma(wr[o2], xv2, acc[o2]);
  }
  float4* Pn = (float4*)(P + (size_t)i * 64);
#pragma unroll
  for (int o4 = 0; o4 < 16; o4++)
    Pn[o4] = make_float4(acc[2 * o4].x, acc[2 * o4].y, acc[2 * o4 + 1].x, acc[2 * o4 + 1].y);
}

// ------- mega: blocks 0-7 fps (r8-proven 512t scalar body), 8-135 xyzt,
//         136-263 pproj0, 264-391 pproj1
__global__ __launch_bounds__(512) void mega_kernel(const float* __restrict__ xyz,
                                                   const float* __restrict__ pts,
                                                   const float* __restrict__ w00,
                                                   const float* __restrict__ b00,
                                                   const float* __restrict__ w10,
                                                   const float* __restrict__ b10,
                                                   float4* __restrict__ xyzT,
                                                   float4* __restrict__ nx,
                                                   float* __restrict__ out0,
                                                   float* __restrict__ P0,
                                                   float* __restrict__ P1) {
  __shared__ alignas(16) char smemc[102528];
  int bid = blockIdx.x, t = threadIdx.x;
  if (bid < 8) {
    float* xs = (float*)smemc;
    float* ys = xs + Nc;
    float* zs = ys + Nc;
    int* idxs = (int*)(smemc + 98304);
    unsigned long long* red = (unsigned long long*)(smemc + 102400);  // [2][8]
    const float* xb = xyz + (size_t)bid * 3 * Nc;
    float px[16], py[16], pz[16], dd[16];
#pragma unroll
    for (int j = 0; j < 16; j++) {
      int n = j * 512 + t;
      float x = xb[n], y = xb[Nc + n], z = xb[2 * Nc + n];
      px[j] = x; py[j] = y; pz[j] = z;
      xs[n] = x; ys[n] = y; zs[n] = z;
      dd[j] = 1e10f;
    }
    int w = t >> 6;
    __syncthreads();
    int curIdx = 0;
    for (int i = 0; i < Sc; i++) {
      float cx = xs[curIdx], cy = ys[curIdx], cz = zs[curIdx];  // LDS broadcast
      if (t == 0) idxs[i] = curIdx;
      float bd = -1.f;
      int bnidx = 0;
#pragma unroll
      for (int j = 0; j < 16; j++) {
        float dx = px[j] - cx, dy = py[j] - cy, dz = pz[j] - cz;
        float d = fmaf(dz, dz, fmaf(dy, dy, dx * dx));
        d = fminf(dd[j], d);
        dd[j] = d;
        if (d > bd) { bd = d; bnidx = j * 512 + t; }  // strict >: first index wins (jnp.argmax)
      }
      unsigned long long key =
          ((unsigned long long)__float_as_uint(bd) << 32) | (unsigned)(~bnidx);
      key = dpp_maxu64<0x111, 0xF>(key);
      key = dpp_maxu64<0x112, 0xF>(key);
      key = dpp_maxu64<0x114, 0xF>(key);
      key = dpp_maxu64<0x118, 0xF>(key);
      key = dpp_maxu64<0x142, 0xA>(key);
      key = dpp_maxu64<0x143, 0xC>(key);
      if ((t & 63) == 63) red[(i & 1) * 8 + w] = key;
      __syncthreads();
      const unsigned long long* rr = red + (i & 1) * 8;
      unsigned long long k2 = rr[0];
#pragma unroll
      for (int u = 1; u < 8; u++) {
        unsigned long long o = rr[u];
        k2 = (o > k2) ? o : k2;
      }
      curIdx = (int)(~(unsigned)(k2 & 0xFFFFFFFFull));
    }
    __syncthreads();
    for (int i2 = t; i2 < Sc; i2 += 512) {
      int idx = idxs[i2];
      float x = xs[idx], y = ys[idx], z = zs[idx];
      nx[bid * Sc + i2] = make_float4(x, y, z, fmaf(z, z, fmaf(y, y, x * x)));
      float* ob = out0 + (size_t)bid * 3 * Sc;
      ob[i2] = x; ob[Sc + i2] = y; ob[2 * Sc + i2] = z;
    }
  } else if (bid < 136) {
    int i = (bid - 8) * 512 + t;
    int b = i >> 13, n = i & 8191;
    const float* xb = xyz + (size_t)b * 3 * Nc;
    float x = xb[n], y = xb[Nc + n], z = xb[2 * Nc + n];
    xyzT[i] = make_float4(x, y, z, fmaf(z, z, fmaf(y, y, x * x)));
  } else {
    bool second = bid >= 264;
    const float* ww = second ? w10 : w00;
    const float* bb = second ? b10 : b00;
    float* PP = second ? P1 : P0;
    float* wl = (float*)smemc;  // 64*64 floats
    float* bl = wl + 64 * 64;
    for (int i2 = t; i2 < 64 * 64; i2 += 512) {
      int c = i2 >> 6, o = i2 & 63;
      wl[i2] = ww[o * 67 + 3 + c];
    }
    if (t < 64) bl[t] = bb[t];
    __syncthreads();
    pproj_body(((bid - (second ? 264 : 136)) * 512) + t, pts, wl, bl, PP);
  }
}

// ---------------- wave-cooperative 32-NN: sorted-insertion updates ----------------
__global__ __launch_bounds__(256) void knn_kernel(const float4* __restrict__ xyzT,
                                                  const float4* __restrict__ newxyz,
                                                  int* __restrict__ knn) {
  int lane = threadIdx.x & 63;
  int sub = lane >> 5;
  int l32 = lane & 31;
  int waveId = blockIdx.x * 4 + (threadIdx.x >> 6);
  int q = waveId * 2 + sub;
  int b = q >> 10;
  float4 qv = newxyz[q];
  const float4* pb = xyzT + (size_t)b * Nc;
  unsigned long long lk = ~0ull;     // sorted asc across 32-group; sentinel = max key
  unsigned long long worst = ~0ull;  // group-uniform copy of lane31's key
  for (int t0 = 0; t0 < Nc; t0 += 32) {
    float4 p = pb[t0 + l32];
    float dot = fmaf(qv.z, p.z, fmaf(qv.y, p.y, qv.x * p.x));
    float d = fmaf(-2.f, dot, qv.w + p.w);  // aa + bb - 2ab, same as reference
    unsigned fu = __float_as_uint(d);
    fu ^= (unsigned)(-(int)(fu >> 31)) | 0x80000000u;  // ordered-uint transform
    unsigned long long ck = ((unsigned long long)fu << 32) | (unsigned)(t0 + l32);
    unsigned long long bal = __ballot(ck < worst);
    unsigned mymask = (unsigned)(bal >> (sub * 32));
    while (mymask) {
      int src = __ffs(mymask) - 1;                     // lowest lane = lowest idx (stable)
      unsigned long long ckb = __shfl(ck, src, 32);    // broadcast candidate key
      unsigned long long bel = __ballot(lk < ckb);
      int cnt = __popc((unsigned)(bel >> (sub * 32))); // insertion rank
      unsigned long long up = __shfl_up(lk, 1, 32);
      lk = (l32 == cnt) ? ckb : ((l32 > cnt) ? up : lk);  // shift-insert, lane31 drops
      worst = __shfl(lk, 31, 32);
      mymask &= ~(1u << src);
      unsigned long long bal2 = __ballot(ck < worst);  // re-filter vs new worst
      mymask &= (unsigned)(bal2 >> (sub * 32));
    }
  }
  knn[(size_t)q * 32 + l32] = (int)(lk & 0xFFFFFFFFu);
}

// ---------------- conv1 body (branch-templated, shared smem carve) ----------------
template <int K>
__device__ __forceinline__ void conv1_body(char* smemc, int bidl,
                                           const float4* __restrict__ xyzT,
                                           const float4* __restrict__ nx,
                                           const int* __restrict__ knn,
                                           const float* __restrict__ P,
                                           const float* __restrict__ w0,
                                           float* __restrict__ y,
                                           float* __restrict__ part, int Pos) {
  v2f* wst = (v2f*)smemc;  // 16*64 v2f = 8192 B
  float* wx = (float*)(smemc + 8192);
  float* wy = wx + 64;
  float* wz = wy + 64;
  if (threadIdx.x < 64) {
    int o = threadIdx.x;
    wx[o] = w0[o * 67];
    wy[o] = w0[o * 67 + 1];
    wz[o] = w0[o * 67 + 2];
  }
  __syncthreads();
  int gp = bidl * 256 + threadIdx.x;
  int b = gp / Pos, r = gp % Pos;
  int s = r / K, kk = r & (K - 1);
  int n = knn[((size_t)(b * Sc + s)) * 32 + kk];
  float4 c4 = nx[b * Sc + s];
  float4 p4 = xyzT[(size_t)b * Nc + n];
  v2f dx2 = {p4.x - c4.x, p4.x - c4.x};
  v2f dy2 = {p4.y - c4.y, p4.y - c4.y};
  v2f dz2 = {p4.z - c4.z, p4.z - c4.z};
  const float4* Pn = (const float4*)(P + ((size_t)b * Nc + n) * 64);
  v2f acc[32];
#pragma unroll
  for (int o4 = 0; o4 < 16; o4++) {
    float4 v = Pn[o4];
    acc[2 * o4] = (v2f){v.x, v.y};
    acc[2 * o4 + 1] = (v2f){v.z, v.w};
  }
  const v2f* wx2 = (const v2f*)wx;
  const v2f* wy2 = (const v2f*)wy;
  const v2f* wz2 = (const v2f*)wz;
#pragma unroll
  for (int o2 = 0; o2 < 32; o2++) acc[o2] = __builtin_elementwise_fma(wx2[o2], dx2, acc[o2]);
#pragma unroll
  for (int o2 = 0; o2 < 32; o2++) acc[o2] = __builtin_elementwise_fma(wy2[o2], dy2, acc[o2]);
#pragma unroll
  for (int o2 = 0; o2 < 32; o2++) acc[o2] = __builtin_elementwise_fma(wz2[o2], dz2, acc[o2]);
  float4* yb = (float4*)(y + ((size_t)b * Pos + r) * 64);
#pragma unroll
  for (int o4 = 0; o4 < 16; o4++)
    yb[o4] = make_float4(acc[2 * o4].x, acc[2 * o4].y, acc[2 * o4 + 1].x, acc[2 * o4 + 1].y);
  int lane = threadIdx.x & 63, w = threadIdx.x >> 6;
  int row = w * 4 + (lane >> 4);
  bool lead = (lane & 15) == 15;
#pragma unroll
  for (int o2 = 0; o2 < 32; o2++) {
    float v0 = acc[o2].x, v1 = acc[o2].y;
    v2f s0 = (v2f){v0, v0 * v0};
    s0 = dpp_sumstep2<0x111, 0xF>(s0);
    s0 = dpp_sumstep2<0x112, 0xF>(s0);
    s0 = dpp_sumstep2<0x114, 0xF>(s0);
    s0 = dpp_sumstep2<0x118, 0xF>(s0);
    v2f s1 = (v2f){v1, v1 * v1};
    s1 = dpp_sumstep2<0x111, 0xF>(s1);
    s1 = dpp_sumstep2<0x112, 0xF>(s1);
    s1 = dpp_sumstep2<0x114, 0xF>(s1);
    s1 = dpp_sumstep2<0x118, 0xF>(s1);
    if (lead) { wst[row * 64 + 2 * o2] = s0; wst[row * 64 + 2 * o2 + 1] = s1; }
  }
  __syncthreads();
  if (threadIdx.x < 64) {
    int o = threadIdx.x;
    v2f sv = (v2f){0.f, 0.f};
#pragma unroll
    for (int rr = 0; rr < 16; rr++) sv += wst[rr * 64 + o];
    ((v2f*)part)[(size_t)bidl * 64 + o] = sv;
  }
}

__global__ __launch_bounds__(256) void conv1M_kernel(
    const float4* xyzT, const float4* nx, const int* knn,
    const float* P0, const float* w0a, float* y0a, float* part0, int Pos0,
    const float* P1, const float* w0b, float* y0b, float* part1, int Pos1, int split) {
  __shared__ alignas(16) char smemc[8960];
  if ((int)blockIdx.x < split)
    conv1_body<16>(smemc, blockIdx.x, xyzT, nx, knn, P0, w0a, y0a, part0, Pos0);
  else
    conv1_body<32>(smemc, blockIdx.x - split, xyzT, nx, knn, P1, w0b, y0b, part1, Pos1);
}

// ---------------- bn finalize (merged, runtime C) ----------------
__global__ __launch_bounds__(256) void bnfinM_kernel(
    const float* part0, const float* g0, const float* be0, float* bn0, int C0, int nblk0, float inv0,
    const float* part1, const float* g1, const float* be1, float* bn1, int C1, int nblk1, float inv1,
    int split) {
  const float* part; const float* g; const float* be; float* bn;
  int C, nblk, c; float invcnt;
  if ((int)blockIdx.x < split) {
    part = part0; g = g0; be = be0; bn = bn0; C = C0; nblk = nblk0; invcnt = inv0; c = blockIdx.x;
  } else {
    part = part1; g = g1; be = be1; bn = bn1; C = C1; nblk = nblk1; invcnt = inv1; c = blockIdx.x - split;
  }
  v2f sq = (v2f){0.f, 0.f};
  for (int i = threadIdx.x; i < nblk; i += 256) sq += ((const v2f*)part)[(size_t)i * C + c];
  sq = dpp_sum64v2(sq);
  __shared__ v2f ls[4];
  int w = threadIdx.x >> 6;
  if ((threadIdx.x & 63) == 63) ls[w] = sq;
  __syncthreads();
  if (threadIdx.x == 0) {
    v2f tt = ls[0] + ls[1] + ls[2] + ls[3];
    float m = tt.x * invcnt;
    float v = tt.y * invcnt - m * m;
    float sc = g[c] / sqrtf(v + BN_EPS);
    bn[c * 2] = sc;
    bn[c * 2 + 1] = fmaf(-m, sc, be[c]);
  }
}

// ---------------- convB body (shared smem carve) ----------------
template <int CI, int CO, int K>
__device__ __forceinline__ void convB_body(char* smemc, int bidl,
                                           const float* __restrict__ yin,
                                           const float* __restrict__ wt,
                                           const float* __restrict__ bb,
                                           const float* __restrict__ bn,
                                           float* __restrict__ yout,
                                           float* __restrict__ ymax,
                                           float* __restrict__ ymin,
                                           float* __restrict__ part, int Pos) {
  constexpr int COq = CO / 4;
  constexpr int COq2 = COq / 2;
  float* wl = (float*)smemc;       // CI*CO
  float* bnl = wl + CI * CO;       // 2*CI
  float* bl = bnl + 2 * CI;        // CO
  for (int i = threadIdx.x; i < CI * CO; i += 256) {
    int c = i / CO, o = i % CO;
    wl[i] = wt[o * CI + c];
  }
  for (int i = threadIdx.x; i < 2 * CI; i += 256) bnl[i] = bn[i];
  if (threadIdx.x < CO) bl[threadIdx.x] = bb[threadIdx.x];
  __syncthreads();
  int w = threadIdx.x >> 6, l = threadIdx.x & 63;
  int cb = w * COq;
  int bpb = Pos / 256;
  int b = bidl / bpb;
  int r0 = (bidl % bpb) * 256 + l * 4;
  const float* xin = yin + ((size_t)b * Pos + r0) * CI;
  v2f acc[4][COq2];
#pragma unroll
  for (int p = 0; p < 4; p++)
#pragma unroll
    for (int q = 0; q < COq2; q++) acc[p][q] = ((const v2f*)(bl + cb))[q];
  float4 cur[4], nxt[4];
#pragma unroll
  for (int p = 0; p < 4; p++) cur[p] = ((const float4*)(xin + p * CI))[0];
  for (int ch = 0; ch < CI; ch += 4) {
    if (ch + 4 < CI) {
#pragma unroll
      for (int p = 0; p < 4; p++) nxt[p] = ((const float4*)(xin + p * CI))[(ch >> 2) + 1];
    }
#pragma unroll
    for (int cc = 0; cc < 4; cc++) {
      int c = ch + cc;
      float scv = bnl[2 * c], shv = bnl[2 * c + 1];
      float xv0 = fmaxf(fmaf(((const float*)&cur[0])[cc], scv, shv), 0.f);
      float xv1 = fmaxf(fmaf(((const float*)&cur[1])[cc], scv, shv), 0.f);
      float xv2 = fmaxf(fmaf(((const float*)&cur[2])[cc], scv, shv), 0.f);
      float xv3 = fmaxf(fmaf(((const float*)&cur[3])[cc], scv, shv), 0.f);
      v2f x0 = {xv0, xv0}, x1 = {xv1, xv1}, x2 = {xv2, xv2}, x3 = {xv3, xv3};
      const float4* wr = (const float4*)(wl + c * CO + cb);
#pragma unroll
      for (int o4 = 0; o4 < COq / 4; o4++) {
        float4 wv = wr[o4];
        v2f w01 = {wv.x, wv.y}, w23 = {wv.z, wv.w};
        acc[0][2 * o4] = __builtin_elementwise_fma(w01, x0, acc[0][2 * o4]);
        acc[0][2 * o4 + 1] = __builtin_elementwise_fma(w23, x0, acc[0][2 * o4 + 1]);
        acc[1][2 * o4] = __builtin_elementwise_fma(w01, x1, acc[1][2 * o4]);
        acc[1][2 * o4 + 1] = __builtin_elementwise_fma(w23, x1, acc[1][2 * o4 + 1]);
        acc[2][2 * o4] = __builtin_elementwise_fma(w01, x2, acc[2][2 * o4]);
        acc[2][2 * o4 + 1] = __builtin_elementwise_fma(w23, x2, acc[2][2 * o4 + 1]);
        acc[3][2 * o4] = __builtin_elementwise_fma(w01, x3, acc[3][2 * o4]);
        acc[3][2 * o4 + 1] = __builtin_elementwise_fma(w23, x3, acc[3][2 * o4 + 1]);
      }
    }
#pragma unroll
    for (int p = 0; p < 4; p++) cur[p] = nxt[p];
  }
  if (K == 0) {
#pragma unroll
    for (int p = 0; p < 4; p++) {
      float4* yo = (float4*)(yout + ((size_t)b * Pos + r0 + p) * CO + cb);
#pragma unroll
      for (int o4 = 0; o4 < COq / 4; o4++)
        yo[o4] = make_float4(acc[p][2 * o4].x, acc[p][2 * o4].y, acc[p][2 * o4 + 1].x,
                             acc[p][2 * o4 + 1].y);
    }
  } else {
    int s = r0 / K;
    bool wrt = (K == 16) ? ((l & 3) == 3) : ((l & 7) == 7);
#pragma unroll
    for (int q = 0; q < COq2; q++) {
      v2f mx = __builtin_elementwise_max(__builtin_elementwise_max(acc[0][q], acc[1][q]),
                                         __builtin_elementwise_max(acc[2][q], acc[3][q]));
      v2f mn = __builtin_elementwise_min(__builtin_elementwise_min(acc[0][q], acc[1][q]),
                                         __builtin_elementwise_min(acc[2][q], acc[3][q]));
      mx = dpp_pkmax<0x111>(mx);
      mx = dpp_pkmax<0x112>(mx);
      if (K == 32) mx = dpp_pkmax<0x114>(mx);
      mn = dpp_pkmin<0x111>(mn);
      mn = dpp_pkmin<0x112>(mn);
      if (K == 32) mn = dpp_pkmin<0x114>(mn);
      if (wrt) {
        ymax[((size_t)b * CO + cb + 2 * q) * Sc + s] = mx.x;
        ymax[((size_t)b * CO + cb + 2 * q + 1) * Sc + s] = mx.y;
        ymin[((size_t)b * CO + cb + 2 * q) * Sc + s] = mn.x;
        ymin[((size_t)b * CO + cb + 2 * q + 1) * Sc + s] = mn.y;
      }
    }
  }
#pragma unroll
  for (int q = 0; q < COq2; q++) {
    v2f sv = acc[0][q] + acc[1][q] + acc[2][q] + acc[3][q];
    v2f sq = acc[0][q] * acc[0][q];
    sq = __builtin_elementwise_fma(acc[1][q], acc[1][q], sq);
    sq = __builtin_elementwise_fma(acc[2][q], acc[2][q], sq);
    sq = __builtin_elementwise_fma(acc[3][q], acc[3][q], sq);
    sv = dpp_sum64v2(sv);
    sq = dpp_sum64v2(sq);
    if (l == 63) {
      ((v2f*)part)[(size_t)bidl * CO + cb + 2 * q] = (v2f){sv.x, sq.x};
      ((v2f*)part)[(size_t)bidl * CO + cb + 2 * q + 1] = (v2f){sv.y, sq.y};
    }
  }
}

__global__ __launch_bounds__(256) void conv2M_kernel(
    const float* y0a, const float* w1a, const float* b1a, const float* bn1a, float* y1a,
    float* part0, int Pos0,
    const float* y0b, const float* w1b, const float* b1b, const float* bn1b, float* y1b,
    float* part1, int Pos1, int split) {
  __shared__ alignas(16) char smemc[25472];
  if ((int)blockIdx.x < split)
    convB_body<64, 64, 0>(smemc, blockIdx.x, y0a, w1a, b1a, bn1a, y1a, nullptr, nullptr, part0, Pos0);
  else
    convB_body<64, 96, 0>(smemc, blockIdx.x - split, y0b, w1b, b1b, bn1b, y1b, nullptr, nullptr, part1, Pos1);
}

__global__ __launch_bounds__(256) void conv3M_kernel(
    const float* y1a, const float* w2a, const float* b2a, const float* bn2a, float* ymax0,
    float* ymin0, float* part0, int Pos0,
    const float* y1b, const float* w2b, const float* b2b, const float* bn2b, float* ymax1,
    float* ymin1, float* part1, int Pos1, int split) {
  __shared__ alignas(16) char smemc[50432];
  if ((int)blockIdx.x < split)
    convB_body<64, 128, 16>(smemc, blockIdx.x, y1a, w2a, b2a, bn2a, nullptr, ymax0, ymin0, part0, Pos0);
  else
    convB_body<96, 128, 32>(smemc, blockIdx.x - split, y1b, w2b, b2b, bn2b, nullptr, ymax1, ymin1, part1, Pos1);
}

// ------- bnfin3 fused with finout (merged) -------
__global__ __launch_bounds__(256) void bnfin3fM_kernel(
    const float* part0, const float* g0, const float* be0, const float* ymax0,
    const float* ymin0, int nblk0, float inv0, int coff0,
    const float* part1, const float* g1, const float* be1, const float* ymax1,
    const float* ymin1, int nblk1, float inv1, int coff1,
    float* out1, int split) {
  constexpr int C = 128;
  const float* part; const float* g; const float* be; const float* ymaxp; const float* yminp;
  int nblk, c, coff; float invcnt;
  if ((int)blockIdx.x < split) {
    part = part0; g = g0; be = be0; ymaxp = ymax0; yminp = ymin0;
    nblk = nblk0; invcnt = inv0; coff = coff0; c = blockIdx.x;
  } else {
    part = part1; g = g1; be = be1; ymaxp = ymax1; yminp = ymin1;
    nblk = nblk1; invcnt = inv1; coff = coff1; c = blockIdx.x - split;
  }
  v2f sq = (v2f){0.f, 0.f};
  for (int i = threadIdx.x; i < nblk; i += 256) sq += ((const v2f*)part)[(size_t)i * C + c];
  sq = dpp_sum64v2(sq);
  __shared__ v2f ls[4];
  __shared__ float bnc[2];
  int w = threadIdx.x >> 6;
  if ((threadIdx.x & 63) == 63) ls[w] = sq;
  __syncthreads();
  if (threadIdx.x == 0) {
    v2f tt = ls[0] + ls[1] + ls[2] + ls[3];
    float m = tt.x * invcnt;
    float v = tt.y * invcnt - m * m;
    float sc = g[c] / sqrtf(v + BN_EPS);
    bnc[0] = sc;
    bnc[1] = fmaf(-m, sc, be[c]);
  }
  __syncthreads();
  float sc = bnc[0], sh = bnc[1];
  const float* src = (sc >= 0.f) ? ymaxp : yminp;  // ReLU∘affine monotone; max over k
#pragma unroll
  for (int k = 0; k < 32; k++) {
    int i = k * 256 + threadIdx.x;  // 8 batches * 1024 s
    int b = i >> 10, s = i & 1023;
    float v = src[((size_t)b * C + c) * Sc + s];
    out1[((size_t)b * 256 + coff + c) * Sc + s] = fmaxf(fmaf(v, sc, sh), 0.f);
  }
}

extern "C" void kernel_launch(void* const* d_in, const int* in_sizes, int n_in,
                              void* d_out, int out_size, void* d_ws, size_t ws_size,
                              hipStream_t stream) {
  const float* xyz = (const float*)d_in[0];
  const float* pts = (const float*)d_in[1];
  float* ws = (float*)d_ws;
  float* out0 = (float*)d_out;
  float* out1 = out0 + Bc * 3 * Sc;

  float4* xyzT = (float4*)(ws + 0);
  float4* nx = (float4*)(ws + 262144);
  int* knnp = (int*)(ws + 294912);
  float* P0 = ws + 557056;

  const float* d2 = (const float*)d_in[2];
  const float* d3 = (const float*)d_in[3];
  const float* d4 = (const float*)d_in[4];
  const float* d5 = (const float*)d_in[5];
  const float* d6 = (const float*)d_in[6];
  const float* d7 = (const float*)d_in[7];
  const float* d8 = (const float*)d_in[8];
  const float* d9 = (const float*)d_in[9];
  const float* d10 = (const float*)d_in[10];
  const float* d11 = (const float*)d_in[11];
  const float* d12 = (const float*)d_in[12];
  const float* d13 = (const float*)d_in[13];
  const float* d14 = (const float*)d_in[14];
  const float* d15 = (const float*)d_in[15];
  const float* d16 = (const float*)d_in[16];
  const float* d17 = (const float*)d_in[17];
  const float* d18 = (const float*)d_in[18];
  const float* d19 = (const float*)d_in[19];
  const float* d20 = (const float*)d_in[20];
  const float* d21 = (const float*)d_in[21];
  const float* d22 = (const float*)d_in[22];
  const float* d23 = (const float*)d_in[23];
  const float* d24 = (const float*)d_in[24];
  const float* d25 = (const float*)d_in[25];

  float inv0 = 1.f / (float)(Bc * 16384);
  float inv1 = 1.f / (float)(Bc * 32768);

  bool merged = ws_size >= (size_t)72254464 * 4;
  if (merged) {
    float* P1 = ws + 4751360;
    float* y00 = ws + 8945664;
    float* y01 = ws + 17334272;
    float* y10 = ws + 34111488;
    float* y11 = ws + 42500096;
    float* ymax0 = ws + 67665920;
    float* ymin0 = ws + 68714496;
    float* ymax1 = ws + 69763072;
    float* ymin1 = ws + 70811648;
    float* part0 = ws + 71860224;
    float* part1 = ws + 71991296;
    float* bns = ws + 72253440;
    float* bn10 = bns, *bn11 = bns + 256, *bn20 = bns + 512, *bn21 = bns + 768;

    mega_kernel<<<392, 512, 0, stream>>>(xyz, pts, d2, d3, d14, d15, xyzT, nx, out0, P0, P1);
    knn_kernel<<<1024, 256, 0, stream>>>(xyzT, nx, knnp);
    conv1M_kernel<<<1536, 256, 0, stream>>>(xyzT, nx, knnp, P0, d2, y00, part0, 16384, P1, d14,
                                            y01, part1, 32768, 512);
    bnfinM_kernel<<<128, 256, 0, stream>>>(part0, d4, d5, bn10, 64, 512, inv0, part1, d16, d17,
                                           bn11, 64, 1024, inv1, 64);
    conv2M_kernel<<<1536, 256, 0, stream>>>(y00, d6, d7, bn10, y10, part0, 16384, y01, d18, d19,
                                            bn11, y11, part1, 32768, 512);
    bnfinM_kernel<<<160, 256, 0, stream>>>(part0, d8, d9, bn20, 64, 512, inv0, part1, d20, d21,
                                           bn21, 96, 1024, inv1, 64);
    conv3M_kernel<<<1536, 256, 0, stream>>>(y10, d10, d11, bn20, ymax0, ymin0, part0, 16384, y11,
                                            d22, d23, bn21, ymax1, ymin1, part1, 32768, 512);
    bnfin3fM_kernel<<<256, 256, 0, stream>>>(part0, d12, d13, ymax0, ymin0, 512, inv0, 0, part1,
                                             d24, d25, ymax1, ymin1, 1024, inv1, 128, out1, 128);
  } else {
    float* y0 = ws + 4751360;
    float* y1 = ws + 21528576;
    float* P1 = ws + 29917184;  // aliases y1 tail; clobbered only by conv2-br1
    float* ymax = ws + 46694400;
    float* ymin = ws + 47742976;
    float* part = ws + 48791552;
    float* bn1 = ws + 49053696;
    float* bn2 = ws + 49053824;

    mega_kernel<<<392, 512, 0, stream>>>(xyz, pts, d2, d3, d14, d15, xyzT, nx, out0, P0, P1);
    knn_kernel<<<1024, 256, 0, stream>>>(xyzT, nx, knnp);

    conv1M_kernel<<<512, 256, 0, stream>>>(xyzT, nx, knnp, P0, d2, y0, part, 16384, P0, d2, y0,
                                           part, 16384, 512);
    bnfinM_kernel<<<64, 256, 0, stream>>>(part, d4, d5, bn1, 64, 512, inv0, part, d4, d5, bn1, 64,
                                          512, inv0, 64);
    conv2M_kernel<<<512, 256, 0, stream>>>(y0, d6, d7, bn1, y1, part, 16384, y0, d6, d7, bn1, y1,
                                           part, 16384, 512);
    bnfinM_kernel<<<64, 256, 0, stream>>>(part, d8, d9, bn2, 64, 512, inv0, part, d8, d9, bn2, 64,
                                          512, inv0, 64);
    conv3M_kernel<<<512, 256, 0, stream>>>(y1, d10, d11, bn2, ymax, ymin, part, 16384, y1, d10,
                                           d11, bn2, ymax, ymin, part, 16384, 512);
    bnfin3fM_kernel<<<128, 256, 0, stream>>>(part, d12, d13, ymax, ymin, 512, inv0, 0, part, d12,
                                             d13, ymax, ymin, 512, inv0, 0, out1, 128);

    conv1M_kernel<<<1024, 256, 0, stream>>>(xyzT, nx, knnp, P1, d14, y0, part, 32768, P1, d14, y0,
                                            part, 32768, 0);
    bnfinM_kernel<<<64, 256, 0, stream>>>(part, d16, d17, bn1, 64, 1024, inv1, part, d16, d17,
                                          bn1, 64, 1024, inv1, 0);
    conv2M_kernel<<<1024, 256, 0, stream>>>(y0, d18, d19, bn1, y1, part, 32768, y0, d18, d19, bn1,
                                            y1, part, 32768, 0);
    bnfinM_kernel<<<96, 256, 0, stream>>>(part, d20, d21, bn2, 96, 1024, inv1, part, d20, d21,
                                          bn2, 96, 1024, inv1, 0);
    conv3M_kernel<<<1024, 256, 0, stream>>>(y1, d22, d23, bn2, ymax, ymin, part, 32768, y1, d22,
                                            d23, bn2, ymax, ymin, part, 32768, 0);
    bnfin3fM_kernel<<<128, 256, 0, stream>>>(part, d24, d25, ymax, ymin, 1024, inv1, 128, part,
                                             d24, d25, ymax, ymin, 1024, inv1, 128, out1, 0);
  }
  (void)in_sizes; (void)n_in; (void)out_size; (void)ws_size;
}

// Round 15
// 1298.341 us; speedup vs baseline: 1.1968x; 1.0686x over previous
//
#include <hip/hip_runtime.h>
#include <math.h>

#define BN_EPS 1e-5f
constexpr int Bc = 8, Nc = 8192, Sc = 1024, CINc = 64;

typedef float v2f __attribute__((ext_vector_type(2)));

// ---------------- DPP helpers ----------------
template <int CTRL, int RMASK>
__device__ __forceinline__ unsigned long long dpp_maxu64(unsigned long long k) {
  int lo = (int)(unsigned)k, hi = (int)(unsigned)(k >> 32);
  int olo = __builtin_amdgcn_update_dpp(lo, lo, CTRL, RMASK, 0xF, false);
  int ohi = __builtin_amdgcn_update_dpp(hi, hi, CTRL, RMASK, 0xF, false);
  unsigned long long ok = ((unsigned long long)(unsigned)ohi << 32) | (unsigned)olo;
  return ok > k ? ok : k;
}
template <int CTRL, int RMASK>
__device__ __forceinline__ v2f dpp_sumstep2(v2f v) {
  int olo = __builtin_amdgcn_update_dpp(0, __float_as_int(v.x), CTRL, RMASK, 0xF, false);
  int ohi = __builtin_amdgcn_update_dpp(0, __float_as_int(v.y), CTRL, RMASK, 0xF, false);
  v2f o = {__int_as_float(olo), __int_as_float(ohi)};
  return v + o;
}
__device__ __forceinline__ v2f dpp_sum64v2(v2f v) {
  v = dpp_sumstep2<0x111, 0xF>(v);
  v = dpp_sumstep2<0x112, 0xF>(v);
  v = dpp_sumstep2<0x114, 0xF>(v);
  v = dpp_sumstep2<0x118, 0xF>(v);
  v = dpp_sumstep2<0x142, 0xA>(v);
  v = dpp_sumstep2<0x143, 0xC>(v);
  return v;  // lane63 holds total
}
template <int CTRL>
__device__ __forceinline__ v2f dpp_pkmax(v2f v) {
  int ox = __builtin_amdgcn_update_dpp(__float_as_int(v.x), __float_as_int(v.x), CTRL, 0xF, 0xF, false);
  int oy = __builtin_amdgcn_update_dpp(__float_as_int(v.y), __float_as_int(v.y), CTRL, 0xF, 0xF, false);
  v2f o = {__int_as_float(ox), __int_as_float(oy)};
  return __builtin_elementwise_max(v, o);
}
template <int CTRL>
__device__ __forceinline__ v2f dpp_pkmin(v2f v) {
  int ox = __builtin_amdgcn_update_dpp(__float_as_int(v.x), __float_as_int(v.x), CTRL, 0xF, 0xF, false);
  int oy = __builtin_amdgcn_update_dpp(__float_as_int(v.y), __float_as_int(v.y), CTRL, 0xF, 0xF, false);
  v2f o = {__int_as_float(ox), __int_as_float(oy)};
  return __builtin_elementwise_min(v, o);
}

// ---------------- shared pproj body (P[n][64] = W_pts . points + bias) ----------------
__device__ __forceinline__ void pproj_body(int i, const float* __restrict__ pts,
                                           const float* __restrict__ wl,
                                           const float* __restrict__ bl,
                                           float* __restrict__ P) {
  int b = i >> 13, n = i & 8191;
  const float* pb = pts + (size_t)b * CINc * Nc + n;
  v2f acc[32];
  const v2f* bl2 = (const v2f*)bl;
#pragma unroll
  for (int o2 = 0; o2 < 32; o2++) acc[o2] = bl2[o2];
  for (int c = 0; c < CINc; c++) {
    float xv = pb[(size_t)c * Nc];
    v2f xv2 = {xv, xv};
    const v2f* wr = (const v2f*)(wl + c * 64);
#pragma unroll
    for (int o2 = 0; o2 < 32; o2++) acc[o2] = __builtin_elementwise_fma(wr[o2], xv2, acc[o2]);
  }
  float4* Pn = (float4*)(P + (size_t)i * 64);
#pragma unroll
  for (int o4 = 0; o4 < 16; o4++)
    Pn[o4] = make_float4(acc[2 * o4].x, acc[2 * o4].y, acc[2 * o4 + 1].x, acc[2 * o4 + 1].y);
}

// ------- mega: blocks 0-7 fps (r8-proven 512t scalar body), 8-135 xyzt,
//         136-263 pproj0, 264-391 pproj1
__global__ __launch_bounds__(512) void mega_kernel(const float* __restrict__ xyz,
                                                   const float* __restrict__ pts,
                                                   const float* __restrict__ w00,
                                                   const float* __restrict__ b00,
                                                   const float* __restrict__ w10,
                                                   const float* __restrict__ b10,
                                                   float4* __restrict__ xyzT,
                                                   float4* __restrict__ nx,
                                                   float* __restrict__ out0,
                                                   float* __restrict__ P0,
                                                   float* __restrict__ P1) {
  __shared__ alignas(16) char smemc[102528];
  int bid = blockIdx.x, t = threadIdx.x;
  if (bid < 8) {
    float* xs = (float*)smemc;
    float* ys = xs + Nc;
    float* zs = ys + Nc;
    int* idxs = (int*)(smemc + 98304);
    unsigned long long* red = (unsigned long long*)(smemc + 102400);  // [2][8]
    const float* xb = xyz + (size_t)bid * 3 * Nc;
    float px[16], py[16], pz[16], dd[16];
#pragma unroll
    for (int j = 0; j < 16; j++) {
      int n = j * 512 + t;
      float x = xb[n], y = xb[Nc + n], z = xb[2 * Nc + n];
      px[j] = x; py[j] = y; pz[j] = z;
      xs[n] = x; ys[n] = y; zs[n] = z;
      dd[j] = 1e10f;
    }
    int w = t >> 6;
    __syncthreads();
    int curIdx = 0;
    for (int i = 0; i < Sc; i++) {
      float cx = xs[curIdx], cy = ys[curIdx], cz = zs[curIdx];  // LDS broadcast
      if (t == 0) idxs[i] = curIdx;
      float bd = -1.f;
      int bnidx = 0;
#pragma unroll
      for (int j = 0; j < 16; j++) {
        float dx = px[j] - cx, dy = py[j] - cy, dz = pz[j] - cz;
        float d = fmaf(dz, dz, fmaf(dy, dy, dx * dx));
        d = fminf(dd[j], d);
        dd[j] = d;
        if (d > bd) { bd = d; bnidx = j * 512 + t; }  // strict >: first index wins (jnp.argmax)
      }
      unsigned long long key =
          ((unsigned long long)__float_as_uint(bd) << 32) | (unsigned)(~bnidx);
      key = dpp_maxu64<0x111, 0xF>(key);
      key = dpp_maxu64<0x112, 0xF>(key);
      key = dpp_maxu64<0x114, 0xF>(key);
      key = dpp_maxu64<0x118, 0xF>(key);
      key = dpp_maxu64<0x142, 0xA>(key);
      key = dpp_maxu64<0x143, 0xC>(key);
      if ((t & 63) == 63) red[(i & 1) * 8 + w] = key;
      __syncthreads();
      const unsigned long long* rr = red + (i & 1) * 8;
      unsigned long long k2 = rr[0];
#pragma unroll
      for (int u = 1; u < 8; u++) {
        unsigned long long o = rr[u];
        k2 = (o > k2) ? o : k2;
      }
      curIdx = (int)(~(unsigned)(k2 & 0xFFFFFFFFull));
    }
    __syncthreads();
    for (int i2 = t; i2 < Sc; i2 += 512) {
      int idx = idxs[i2];
      float x = xs[idx], y = ys[idx], z = zs[idx];
      nx[bid * Sc + i2] = make_float4(x, y, z, fmaf(z, z, fmaf(y, y, x * x)));
      float* ob = out0 + (size_t)bid * 3 * Sc;
      ob[i2] = x; ob[Sc + i2] = y; ob[2 * Sc + i2] = z;
    }
  } else if (bid < 136) {
    int i = (bid - 8) * 512 + t;
    int b = i >> 13, n = i & 8191;
    const float* xb = xyz + (size_t)b * 3 * Nc;
    float x = xb[n], y = xb[Nc + n], z = xb[2 * Nc + n];
    xyzT[i] = make_float4(x, y, z, fmaf(z, z, fmaf(y, y, x * x)));
  } else {
    bool second = bid >= 264;
    const float* ww = second ? w10 : w00;
    const float* bb = second ? b10 : b00;
    float* PP = second ? P1 : P0;
    float* wl = (float*)smemc;  // 64*64 floats
    float* bl = wl + 64 * 64;
    for (int i2 = t; i2 < 64 * 64; i2 += 512) {
      int c = i2 >> 6, o = i2 & 63;
      wl[i2] = ww[o * 67 + 3 + c];
    }
    if (t < 64) bl[t] = bb[t];
    __syncthreads();
    pproj_body(((bid - (second ? 264 : 136)) * 512) + t, pts, wl, bl, PP);
  }
}

// ---------------- wave-cooperative 32-NN: sorted-insertion updates ----------------
__global__ __launch_bounds__(256) void knn_kernel(const float4* __restrict__ xyzT,
                                                  const float4* __restrict__ newxyz,
                                                  int* __restrict__ knn) {
  int lane = threadIdx.x & 63;
  int sub = lane >> 5;
  int l32 = lane & 31;
  int waveId = blockIdx.x * 4 + (threadIdx.x >> 6);
  int q = waveId * 2 + sub;
  int b = q >> 10;
  float4 qv = newxyz[q];
  const float4* pb = xyzT + (size_t)b * Nc;
  unsigned long long lk = ~0ull;     // sorted asc across 32-group; sentinel = max key
  unsigned long long worst = ~0ull;  // group-uniform copy of lane31's key
  for (int t0 = 0; t0 < Nc; t0 += 32) {
    float4 p = pb[t0 + l32];
    float dot = fmaf(qv.z, p.z, fmaf(qv.y, p.y, qv.x * p.x));
    float d = fmaf(-2.f, dot, qv.w + p.w);  // aa + bb - 2ab, same as reference
    unsigned fu = __float_as_uint(d);
    fu ^= (unsigned)(-(int)(fu >> 31)) | 0x80000000u;  // ordered-uint transform
    unsigned long long ck = ((unsigned long long)fu << 32) | (unsigned)(t0 + l32);
    unsigned long long bal = __ballot(ck < worst);
    unsigned mymask = (unsigned)(bal >> (sub * 32));
    while (mymask) {
      int src = __ffs(mymask) - 1;                     // lowest lane = lowest idx (stable)
      unsigned long long ckb = __shfl(ck, src, 32);    // broadcast candidate key
      unsigned long long bel = __ballot(lk < ckb);
      int cnt = __popc((unsigned)(bel >> (sub * 32))); // insertion rank
      unsigned long long up = __shfl_up(lk, 1, 32);
      lk = (l32 == cnt) ? ckb : ((l32 > cnt) ? up : lk);  // shift-insert, lane31 drops
      worst = __shfl(lk, 31, 32);
      mymask &= ~(1u << src);
      unsigned long long bal2 = __ballot(ck < worst);  // re-filter vs new worst
      mymask &= (unsigned)(bal2 >> (sub * 32));
    }
  }
  knn[(size_t)q * 32 + l32] = (int)(lk & 0xFFFFFFFFu);
}

// ---------------- conv1 body: y tiled channel-major [tile][64][256] ----------------
template <int K>
__device__ __forceinline__ void conv1_body(char* smemc, int bidl,
                                           const float4* __restrict__ xyzT,
                                           const float4* __restrict__ nx,
                                           const int* __restrict__ knn,
                                           const float* __restrict__ P,
                                           const float* __restrict__ w0,
                                           float* __restrict__ y,
                                           float* __restrict__ part, int Pos) {
  v2f* wst = (v2f*)smemc;  // 16*64 v2f = 8192 B
  float* wx = (float*)(smemc + 8192);
  float* wy = wx + 64;
  float* wz = wy + 64;
  if (threadIdx.x < 64) {
    int o = threadIdx.x;
    wx[o] = w0[o * 67];
    wy[o] = w0[o * 67 + 1];
    wz[o] = w0[o * 67 + 2];
  }
  __syncthreads();
  int gp = bidl * 256 + threadIdx.x;
  int b = gp / Pos, r = gp % Pos;
  int s = r / K, kk = r & (K - 1);
  int n = knn[((size_t)(b * Sc + s)) * 32 + kk];
  float4 c4 = nx[b * Sc + s];
  float4 p4 = xyzT[(size_t)b * Nc + n];
  v2f dx2 = {p4.x - c4.x, p4.x - c4.x};
  v2f dy2 = {p4.y - c4.y, p4.y - c4.y};
  v2f dz2 = {p4.z - c4.z, p4.z - c4.z};
  const float4* Pn = (const float4*)(P + ((size_t)b * Nc + n) * 64);
  v2f acc[32];
#pragma unroll
  for (int o4 = 0; o4 < 16; o4++) {
    float4 v = Pn[o4];
    acc[2 * o4] = (v2f){v.x, v.y};
    acc[2 * o4 + 1] = (v2f){v.z, v.w};
  }
  const v2f* wx2 = (const v2f*)wx;
  const v2f* wy2 = (const v2f*)wy;
  const v2f* wz2 = (const v2f*)wz;
#pragma unroll
  for (int o2 = 0; o2 < 32; o2++) acc[o2] = __builtin_elementwise_fma(wx2[o2], dx2, acc[o2]);
#pragma unroll
  for (int o2 = 0; o2 < 32; o2++) acc[o2] = __builtin_elementwise_fma(wy2[o2], dy2, acc[o2]);
#pragma unroll
  for (int o2 = 0; o2 < 32; o2++) acc[o2] = __builtin_elementwise_fma(wz2[o2], dz2, acc[o2]);
  // tiled channel-major store: y[tile=bidl][ch][lpos=tid] -- coalesced scalar stores
  float* yt = y + (size_t)bidl * 64 * 256 + threadIdx.x;
#pragma unroll
  for (int o2 = 0; o2 < 32; o2++) {
    yt[(size_t)(2 * o2) * 256] = acc[o2].x;
    yt[(size_t)(2 * o2 + 1) * 256] = acc[o2].y;
  }
  int lane = threadIdx.x & 63, w = threadIdx.x >> 6;
  int row = w * 4 + (lane >> 4);
  bool lead = (lane & 15) == 15;
#pragma unroll
  for (int o2 = 0; o2 < 32; o2++) {
    float v0 = acc[o2].x, v1 = acc[o2].y;
    v2f s0 = (v2f){v0, v0 * v0};
    s0 = dpp_sumstep2<0x111, 0xF>(s0);
    s0 = dpp_sumstep2<0x112, 0xF>(s0);
    s0 = dpp_sumstep2<0x114, 0xF>(s0);
    s0 = dpp_sumstep2<0x118, 0xF>(s0);
    v2f s1 = (v2f){v1, v1 * v1};
    s1 = dpp_sumstep2<0x111, 0xF>(s1);
    s1 = dpp_sumstep2<0x112, 0xF>(s1);
    s1 = dpp_sumstep2<0x114, 0xF>(s1);
    s1 = dpp_sumstep2<0x118, 0xF>(s1);
    if (lead) { wst[row * 64 + 2 * o2] = s0; wst[row * 64 + 2 * o2 + 1] = s1; }
  }
  __syncthreads();
  if (threadIdx.x < 64) {
    int o = threadIdx.x;
    v2f sv = (v2f){0.f, 0.f};
#pragma unroll
    for (int rr = 0; rr < 16; rr++) sv += wst[rr * 64 + o];
    ((v2f*)part)[(size_t)bidl * 64 + o] = sv;
  }
}

__global__ __launch_bounds__(256) void conv1M_kernel(
    const float4* xyzT, const float4* nx, const int* knn,
    const float* P0, const float* w0a, float* y0a, float* part0, int Pos0,
    const float* P1, const float* w0b, float* y0b, float* part1, int Pos1, int split) {
  __shared__ alignas(16) char smemc[8960];
  if ((int)blockIdx.x < split)
    conv1_body<16>(smemc, blockIdx.x, xyzT, nx, knn, P0, w0a, y0a, part0, Pos0);
  else
    conv1_body<32>(smemc, blockIdx.x - split, xyzT, nx, knn, P1, w0b, y0b, part1, Pos1);
}

// ---------------- bn finalize (merged, runtime C) ----------------
__global__ __launch_bounds__(256) void bnfinM_kernel(
    const float* part0, const float* g0, const float* be0, float* bn0, int C0, int nblk0, float inv0,
    const float* part1, const float* g1, const float* be1, float* bn1, int C1, int nblk1, float inv1,
    int split) {
  const float* part; const float* g; const float* be; float* bn;
  int C, nblk, c; float invcnt;
  if ((int)blockIdx.x < split) {
    part = part0; g = g0; be = be0; bn = bn0; C = C0; nblk = nblk0; invcnt = inv0; c = blockIdx.x;
  } else {
    part = part1; g = g1; be = be1; bn = bn1; C = C1; nblk = nblk1; invcnt = inv1; c = blockIdx.x - split;
  }
  v2f sq = (v2f){0.f, 0.f};
  for (int i = threadIdx.x; i < nblk; i += 256) sq += ((const v2f*)part)[(size_t)i * C + c];
  sq = dpp_sum64v2(sq);
  __shared__ v2f ls[4];
  int w = threadIdx.x >> 6;
  if ((threadIdx.x & 63) == 63) ls[w] = sq;
  __syncthreads();
  if (threadIdx.x == 0) {
    v2f tt = ls[0] + ls[1] + ls[2] + ls[3];
    float m = tt.x * invcnt;
    float v = tt.y * invcnt - m * m;
    float sc = g[c] / sqrtf(v + BN_EPS);
    bn[c * 2] = sc;
    bn[c * 2 + 1] = fmaf(-m, sc, be[c]);
  }
}

// ---------------- convB body: y tiled channel-major in/out ----------------
template <int CI, int CO, int K>
__device__ __forceinline__ void convB_body(char* smemc, int bidl,
                                           const float* __restrict__ yin,
                                           const float* __restrict__ wt,
                                           const float* __restrict__ bb,
                                           const float* __restrict__ bn,
                                           float* __restrict__ yout,
                                           float* __restrict__ ymax,
                                           float* __restrict__ ymin,
                                           float* __restrict__ part, int Pos) {
  constexpr int COq = CO / 4;
  constexpr int COq2 = COq / 2;
  float* wl = (float*)smemc;       // CI*CO
  float* bnl = wl + CI * CO;       // 2*CI
  float* bl = bnl + 2 * CI;        // CO
  for (int i = threadIdx.x; i < CI * CO; i += 256) {
    int c = i / CO, o = i % CO;
    wl[i] = wt[o * CI + c];
  }
  for (int i = threadIdx.x; i < 2 * CI; i += 256) bnl[i] = bn[i];
  if (threadIdx.x < CO) bl[threadIdx.x] = bb[threadIdx.x];
  __syncthreads();
  int w = threadIdx.x >> 6, l = threadIdx.x & 63;
  int cb = w * COq;
  int bpb = Pos / 256;
  int b = bidl / bpb;
  int r0 = (bidl % bpb) * 256 + l * 4;
  // tiled channel-major input: tile base + c*256 + 4*l  (coalesced float4 per channel)
  const float4* xt = (const float4*)(yin + (size_t)bidl * CI * 256) + l;
  v2f acc[4][COq2];
#pragma unroll
  for (int p = 0; p < 4; p++)
#pragma unroll
    for (int q = 0; q < COq2; q++) acc[p][q] = ((const v2f*)(bl + cb))[q];
  float4 cur = xt[0], nxt;
  for (int c = 0; c < CI; c++) {
    if (c + 1 < CI) nxt = xt[(c + 1) * 64];
    float scv = bnl[2 * c], shv = bnl[2 * c + 1];
    float xv0 = fmaxf(fmaf(cur.x, scv, shv), 0.f);
    float xv1 = fmaxf(fmaf(cur.y, scv, shv), 0.f);
    float xv2 = fmaxf(fmaf(cur.z, scv, shv), 0.f);
    float xv3 = fmaxf(fmaf(cur.w, scv, shv), 0.f);
    v2f x0 = {xv0, xv0}, x1 = {xv1, xv1}, x2 = {xv2, xv2}, x3 = {xv3, xv3};
    const float4* wr = (const float4*)(wl + c * CO + cb);
#pragma unroll
    for (int o4 = 0; o4 < COq / 4; o4++) {
      float4 wv = wr[o4];
      v2f w01 = {wv.x, wv.y}, w23 = {wv.z, wv.w};
      acc[0][2 * o4] = __builtin_elementwise_fma(w01, x0, acc[0][2 * o4]);
      acc[0][2 * o4 + 1] = __builtin_elementwise_fma(w23, x0, acc[0][2 * o4 + 1]);
      acc[1][2 * o4] = __builtin_elementwise_fma(w01, x1, acc[1][2 * o4]);
      acc[1][2 * o4 + 1] = __builtin_elementwise_fma(w23, x1, acc[1][2 * o4 + 1]);
      acc[2][2 * o4] = __builtin_elementwise_fma(w01, x2, acc[2][2 * o4]);
      acc[2][2 * o4 + 1] = __builtin_elementwise_fma(w23, x2, acc[2][2 * o4 + 1]);
      acc[3][2 * o4] = __builtin_elementwise_fma(w01, x3, acc[3][2 * o4]);
      acc[3][2 * o4 + 1] = __builtin_elementwise_fma(w23, x3, acc[3][2 * o4 + 1]);
    }
    cur = nxt;
  }
  if (K == 0) {
    // tiled channel-major output: per channel one float4 of this thread's 4 positions
    float* yo = yout + (size_t)bidl * CO * 256;
#pragma unroll
    for (int q = 0; q < COq2; q++) {
      ((float4*)(yo + (size_t)(cb + 2 * q) * 256))[l] =
          make_float4(acc[0][q].x, acc[1][q].x, acc[2][q].x, acc[3][q].x);
      ((float4*)(yo + (size_t)(cb + 2 * q + 1) * 256))[l] =
          make_float4(acc[0][q].y, acc[1][q].y, acc[2][q].y, acc[3][q].y);
    }
  } else {
    int s = r0 / K;
    bool wrt = (K == 16) ? ((l & 3) == 3) : ((l & 7) == 7);
#pragma unroll
    for (int q = 0; q < COq2; q++) {
      v2f mx = __builtin_elementwise_max(__builtin_elementwise_max(acc[0][q], acc[1][q]),
                                         __builtin_elementwise_max(acc[2][q], acc[3][q]));
      v2f mn = __builtin_elementwise_min(__builtin_elementwise_min(acc[0][q], acc[1][q]),
                                         __builtin_elementwise_min(acc[2][q], acc[3][q]));
      mx = dpp_pkmax<0x111>(mx);
      mx = dpp_pkmax<0x112>(mx);
      if (K == 32) mx = dpp_pkmax<0x114>(mx);
      mn = dpp_pkmin<0x111>(mn);
      mn = dpp_pkmin<0x112>(mn);
      if (K == 32) mn = dpp_pkmin<0x114>(mn);
      if (wrt) {
        ymax[((size_t)b * CO + cb + 2 * q) * Sc + s] = mx.x;
        ymax[((size_t)b * CO + cb + 2 * q + 1) * Sc + s] = mx.y;
        ymin[((size_t)b * CO + cb + 2 * q) * Sc + s] = mn.x;
        ymin[((size_t)b * CO + cb + 2 * q + 1) * Sc + s] = mn.y;
      }
    }
  }
#pragma unroll
  for (int q = 0; q < COq2; q++) {
    v2f sv = acc[0][q] + acc[1][q] + acc[2][q] + acc[3][q];
    v2f sq = acc[0][q] * acc[0][q];
    sq = __builtin_elementwise_fma(acc[1][q], acc[1][q], sq);
    sq = __builtin_elementwise_fma(acc[2][q], acc[2][q], sq);
    sq = __builtin_elementwise_fma(acc[3][q], acc[3][q], sq);
    sv = dpp_sum64v2(sv);
    sq = dpp_sum64v2(sq);
    if (l == 63) {
      ((v2f*)part)[(size_t)bidl * CO + cb + 2 * q] = (v2f){sv.x, sq.x};
      ((v2f*)part)[(size_t)bidl * CO + cb + 2 * q + 1] = (v2f){sv.y, sq.y};
    }
  }
}

__global__ __launch_bounds__(256) void conv2M_kernel(
    const float* y0a, const float* w1a, const float* b1a, const float* bn1a, float* y1a,
    float* part0, int Pos0,
    const float* y0b, const float* w1b, const float* b1b, const float* bn1b, float* y1b,
    float* part1, int Pos1, int split) {
  __shared__ alignas(16) char smemc[25472];
  if ((int)blockIdx.x < split)
    convB_body<64, 64, 0>(smemc, blockIdx.x, y0a, w1a, b1a, bn1a, y1a, nullptr, nullptr, part0, Pos0);
  else
    convB_body<64, 96, 0>(smemc, blockIdx.x - split, y0b, w1b, b1b, bn1b, y1b, nullptr, nullptr, part1, Pos1);
}

__global__ __launch_bounds__(256) void conv3M_kernel(
    const float* y1a, const float* w2a, const float* b2a, const float* bn2a, float* ymax0,
    float* ymin0, float* part0, int Pos0,
    const float* y1b, const float* w2b, const float* b2b, const float* bn2b, float* ymax1,
    float* ymin1, float* part1, int Pos1, int split) {
  __shared__ alignas(16) char smemc[50432];
  if ((int)blockIdx.x < split)
    convB_body<64, 128, 16>(smemc, blockIdx.x, y1a, w2a, b2a, bn2a, nullptr, ymax0, ymin0, part0, Pos0);
  else
    convB_body<96, 128, 32>(smemc, blockIdx.x - split, y1b, w2b, b2b, bn2b, nullptr, ymax1, ymin1, part1, Pos1);
}

// ------- bnfin3 fused with finout (merged) -------
__global__ __launch_bounds__(256) void bnfin3fM_kernel(
    const float* part0, const float* g0, const float* be0, const float* ymax0,
    const float* ymin0, int nblk0, float inv0, int coff0,
    const float* part1, const float* g1, const float* be1, const float* ymax1,
    const float* ymin1, int nblk1, float inv1, int coff1,
    float* out1, int split) {
  constexpr int C = 128;
  const float* part; const float* g; const float* be; const float* ymaxp; const float* yminp;
  int nblk, c, coff; float invcnt;
  if ((int)blockIdx.x < split) {
    part = part0; g = g0; be = be0; ymaxp = ymax0; yminp = ymin0;
    nblk = nblk0; invcnt = inv0; coff = coff0; c = blockIdx.x;
  } else {
    part = part1; g = g1; be = be1; ymaxp = ymax1; yminp = ymin1;
    nblk = nblk1; invcnt = inv1; coff = coff1; c = blockIdx.x - split;
  }
  v2f sq = (v2f){0.f, 0.f};
  for (int i = threadIdx.x; i < nblk; i += 256) sq += ((const v2f*)part)[(size_t)i * C + c];
  sq = dpp_sum64v2(sq);
  __shared__ v2f ls[4];
  __shared__ float bnc[2];
  int w = threadIdx.x >> 6;
  if ((threadIdx.x & 63) == 63) ls[w] = sq;
  __syncthreads();
  if (threadIdx.x == 0) {
    v2f tt = ls[0] + ls[1] + ls[2] + ls[3];
    float m = tt.x * invcnt;
    float v = tt.y * invcnt - m * m;
    float sc = g[c] / sqrtf(v + BN_EPS);
    bnc[0] = sc;
    bnc[1] = fmaf(-m, sc, be[c]);
  }
  __syncthreads();
  float sc = bnc[0], sh = bnc[1];
  const float* src = (sc >= 0.f) ? ymaxp : yminp;  // ReLU∘affine monotone; max over k
#pragma unroll
  for (int k = 0; k < 32; k++) {
    int i = k * 256 + threadIdx.x;  // 8 batches * 1024 s
    int b = i >> 10, s = i & 1023;
    float v = src[((size_t)b * C + c) * Sc + s];
    out1[((size_t)b * 256 + coff + c) * Sc + s] = fmaxf(fmaf(v, sc, sh), 0.f);
  }
}

extern "C" void kernel_launch(void* const* d_in, const int* in_sizes, int n_in,
                              void* d_out, int out_size, void* d_ws, size_t ws_size,
                              hipStream_t stream) {
  const float* xyz = (const float*)d_in[0];
  const float* pts = (const float*)d_in[1];
  float* ws = (float*)d_ws;
  float* out0 = (float*)d_out;
  float* out1 = out0 + Bc * 3 * Sc;

  float4* xyzT = (float4*)(ws + 0);
  float4* nx = (float4*)(ws + 262144);
  int* knnp = (int*)(ws + 294912);
  float* P0 = ws + 557056;

  const float* d2 = (const float*)d_in[2];
  const float* d3 = (const float*)d_in[3];
  const float* d4 = (const float*)d_in[4];
  const float* d5 = (const float*)d_in[5];
  const float* d6 = (const float*)d_in[6];
  const float* d7 = (const float*)d_in[7];
  const float* d8 = (const float*)d_in[8];
  const float* d9 = (const float*)d_in[9];
  const float* d10 = (const float*)d_in[10];
  const float* d11 = (const float*)d_in[11];
  const float* d12 = (const float*)d_in[12];
  const float* d13 = (const float*)d_in[13];
  const float* d14 = (const float*)d_in[14];
  const float* d15 = (const float*)d_in[15];
  const float* d16 = (const float*)d_in[16];
  const float* d17 = (const float*)d_in[17];
  const float* d18 = (const float*)d_in[18];
  const float* d19 = (const float*)d_in[19];
  const float* d20 = (const float*)d_in[20];
  const float* d21 = (const float*)d_in[21];
  const float* d22 = (const float*)d_in[22];
  const float* d23 = (const float*)d_in[23];
  const float* d24 = (const float*)d_in[24];
  const float* d25 = (const float*)d_in[25];

  float inv0 = 1.f / (float)(Bc * 16384);
  float inv1 = 1.f / (float)(Bc * 32768);

  bool merged = ws_size >= (size_t)72254464 * 4;
  if (merged) {
    float* P1 = ws + 4751360;
    float* y00 = ws + 8945664;
    float* y01 = ws + 17334272;
    float* y10 = ws + 34111488;
    float* y11 = ws + 42500096;
    float* ymax0 = ws + 67665920;
    float* ymin0 = ws + 68714496;
    float* ymax1 = ws + 69763072;
    float* ymin1 = ws + 70811648;
    float* part0 = ws + 71860224;
    float* part1 = ws + 71991296;
    float* bns = ws + 72253440;
    float* bn10 = bns, *bn11 = bns + 256, *bn20 = bns + 512, *bn21 = bns + 768;

    mega_kernel<<<392, 512, 0, stream>>>(xyz, pts, d2, d3, d14, d15, xyzT, nx, out0, P0, P1);
    knn_kernel<<<1024, 256, 0, stream>>>(xyzT, nx, knnp);
    conv1M_kernel<<<1536, 256, 0, stream>>>(xyzT, nx, knnp, P0, d2, y00, part0, 16384, P1, d14,
                                            y01, part1, 32768, 512);
    bnfinM_kernel<<<128, 256, 0, stream>>>(part0, d4, d5, bn10, 64, 512, inv0, part1, d16, d17,
                                           bn11, 64, 1024, inv1, 64);
    conv2M_kernel<<<1536, 256, 0, stream>>>(y00, d6, d7, bn10, y10, part0, 16384, y01, d18, d19,
                                            bn11, y11, part1, 32768, 512);
    bnfinM_kernel<<<160, 256, 0, stream>>>(part0, d8, d9, bn20, 64, 512, inv0, part1, d20, d21,
                                           bn21, 96, 1024, inv1, 64);
    conv3M_kernel<<<1536, 256, 0, stream>>>(y10, d10, d11, bn20, ymax0, ymin0, part0, 16384, y11,
                                            d22, d23, bn21, ymax1, ymin1, part1, 32768, 512);
    bnfin3fM_kernel<<<256, 256, 0, stream>>>(part0, d12, d13, ymax0, ymin0, 512, inv0, 0, part1,
                                             d24, d25, ymax1, ymin1, 1024, inv1, 128, out1, 128);
  } else {
    float* y0 = ws + 4751360;
    float* y1 = ws + 21528576;
    float* P1 = ws + 29917184;  // aliases y1 tail; clobbered only by conv2-br1
    float* ymax = ws + 46694400;
    float* ymin = ws + 47742976;
    float* part = ws + 48791552;
    float* bn1 = ws + 49053696;
    float* bn2 = ws + 49053824;

    mega_kernel<<<392, 512, 0, stream>>>(xyz, pts, d2, d3, d14, d15, xyzT, nx, out0, P0, P1);
    knn_kernel<<<1024, 256, 0, stream>>>(xyzT, nx, knnp);

    conv1M_kernel<<<512, 256, 0, stream>>>(xyzT, nx, knnp, P0, d2, y0, part, 16384, P0, d2, y0,
                                           part, 16384, 512);
    bnfinM_kernel<<<64, 256, 0, stream>>>(part, d4, d5, bn1, 64, 512, inv0, part, d4, d5, bn1, 64,
                                          512, inv0, 64);
    conv2M_kernel<<<512, 256, 0, stream>>>(y0, d6, d7, bn1, y1, part, 16384, y0, d6, d7, bn1, y1,
                                           part, 16384, 512);
    bnfinM_kernel<<<64, 256, 0, stream>>>(part, d8, d9, bn2, 64, 512, inv0, part, d8, d9, bn2, 64,
                                          512, inv0, 64);
    conv3M_kernel<<<512, 256, 0, stream>>>(y1, d10, d11, bn2, ymax, ymin, part, 16384, y1, d10,
                                           d11, bn2, ymax, ymin, part, 16384, 512);
    bnfin3fM_kernel<<<128, 256, 0, stream>>>(part, d12, d13, ymax, ymin, 512, inv0, 0, part, d12,
                                             d13, ymax, ymin, 512, inv0, 0, out1, 128);

    conv1M_kernel<<<1024, 256, 0, stream>>>(xyzT, nx, knnp, P1, d14, y0, part, 32768, P1, d14, y0,
                                            part, 32768, 0);
    bnfinM_kernel<<<64, 256, 0, stream>>>(part, d16, d17, bn1, 64, 1024, inv1, part, d16, d17,
                                          bn1, 64, 1024, inv1, 0);
    conv2M_kernel<<<1024, 256, 0, stream>>>(y0, d18, d19, bn1, y1, part, 32768, y0, d18, d19, bn1,
                                            y1, part, 32768, 0);
    bnfinM_kernel<<<96, 256, 0, stream>>>(part, d20, d21, bn2, 96, 1024, inv1, part, d20, d21,
                                          bn2, 96, 1024, inv1, 0);
    conv3M_kernel<<<1024, 256, 0, stream>>>(y1, d22, d23, bn2, ymax, ymin, part, 32768, y1, d22,
                                            d23, bn2, ymax, ymin, part, 32768, 0);
    bnfin3fM_kernel<<<128, 256, 0, stream>>>(part, d24, d25, ymax, ymin, 1024, inv1, 128, part,
                                             d24, d25, ymax, ymin, 1024, inv1, 128, out1, 0);
  }
  (void)in_sizes; (void)n_in; (void)out_size; (void)ws_size;
}